// Round 4
// baseline (970.567 us; speedup 1.0000x reference)
//
#include <hip/hip_runtime.h>

#define HC 128
#define FIN 128
#define NHEAD 4
#define NS_ATT 0.2f
#define NS_ACT 0.01f

__device__ __forceinline__ float lrelu(float v, float s) { return v >= 0.f ? v : s * v; }

// init: count=1 (self-loop), zero pooling buffers
__global__ void k_init(int* __restrict__ cnt, float* __restrict__ pool_sum,
                       int* __restrict__ pool_cnt, int N, int B) {
  int i = blockIdx.x * 256 + threadIdx.x;
  if (i < N) cnt[i] = 1;
  if (i < B * HC) pool_sum[i] = 0.f;
  if (i < B) pool_cnt[i] = 0;
}

// xh = x @ W  (+ fused a_src/a_dst head-dot epilogue)
__global__ __launch_bounds__(256) void k_gemm(
    const float* __restrict__ x, const float* __restrict__ Wm,
    const float* __restrict__ att_s, const float* __restrict__ att_d,
    float* __restrict__ xh, float* __restrict__ a_src, float* __restrict__ a_dst,
    int N) {
  __shared__ __align__(16) float xs[8][FIN];
  const int tid = threadIdx.x, tx = tid & 127, ty = tid >> 7;
  const long base = (long)blockIdx.x * 64;
  float w[FIN];
#pragma unroll
  for (int k = 0; k < FIN; ++k) w[k] = Wm[k * HC + tx];
  const float asc = att_s[tx], adc = att_d[tx];
  for (int g = 0; g < 8; ++g) {
    const long r0 = base + g * 8;
#pragma unroll
    for (int q = 0; q < 4; ++q) {
      int idx = tid + q * 256;
      int lr = idx >> 7, col = idx & 127;
      long row = r0 + lr;
      xs[lr][col] = (row < N) ? x[row * FIN + col] : 0.f;
    }
    __syncthreads();
#pragma unroll
    for (int ii = 0; ii < 4; ++ii) {
      const int lr = 2 * ii + ty;
      const long row = r0 + lr;
      const float4* xr = (const float4*)xs[lr];
      float acc[4] = {0.f, 0.f, 0.f, 0.f};
#pragma unroll
      for (int k4 = 0; k4 < 32; ++k4) {
        float4 v = xr[k4];
        acc[k4 & 3] = fmaf(v.w, w[4 * k4 + 3],
                      fmaf(v.z, w[4 * k4 + 2],
                      fmaf(v.y, w[4 * k4 + 1],
                      fmaf(v.x, w[4 * k4 + 0], acc[k4 & 3]))));
      }
      float a = (acc[0] + acc[1]) + (acc[2] + acc[3]);
      if (row < N) {
        xh[row * HC + tx] = a;
        float ps = a * asc, pd = a * adc;
#pragma unroll
        for (int m = 16; m >= 1; m >>= 1) {
          ps += __shfl_xor(ps, m);
          pd += __shfl_xor(pd, m);
        }
        if ((tx & 31) == 0) {
          int h = tx >> 5;
          a_src[row * NHEAD + h] = ps;
          a_dst[row * NHEAD + h] = pd;
        }
      }
    }
    __syncthreads();
  }
}

__global__ void k_count(const int* __restrict__ ei, int* __restrict__ cnt, int E) {
  int i = blockIdx.x * 256 + threadIdx.x;
  if (i < E) atomicAdd(&cnt[ei[E + i]], 1);
}

__global__ void k_scanA(const int* __restrict__ cnt, int* __restrict__ offs,
                        int* __restrict__ part, int N) {
  __shared__ int s[256];
  int t = threadIdx.x, i = blockIdx.x * 256 + t;
  int v = (i < N) ? cnt[i] : 0;
  s[t] = v;
#pragma unroll
  for (int off = 1; off < 256; off <<= 1) {
    __syncthreads();
    int u = (t >= off) ? s[t - off] : 0;
    __syncthreads();
    s[t] += u;
  }
  if (i < N) offs[i] = s[t] - v;
  if (t == 255) part[blockIdx.x] = s[255];
}

__global__ void k_scanB(int* __restrict__ part, int NB) {
  __shared__ int s[1024];
  int t = threadIdx.x;
  int v = (t < NB) ? part[t] : 0;
  s[t] = v;
#pragma unroll
  for (int off = 1; off < 1024; off <<= 1) {
    __syncthreads();
    int u = (t >= off) ? s[t - off] : 0;
    __syncthreads();
    s[t] += u;
  }
  if (t < NB) part[t] = s[t] - v;
  if (t == 1023) part[NB] = s[1023];
}

__global__ void k_scanC(int* __restrict__ offs, const int* __restrict__ part, int N, int NB) {
  int i = blockIdx.x * 256 + threadIdx.x;
  if (i < N) offs[i] += part[i >> 8];
  else if (i == N) offs[N] = part[NB];
}

__global__ void k_selfloop(const int* __restrict__ offs, int* __restrict__ cursor,
                           int* __restrict__ csr_src, int N) {
  int i = blockIdx.x * 256 + threadIdx.x;
  if (i < N) {
    int o = offs[i];
    cursor[i] = o + 1;
    csr_src[o] = i;
  }
}

__global__ void k_fill(const int* __restrict__ ei, int* __restrict__ cursor,
                       int* __restrict__ csr_src, int E) {
  int i = blockIdx.x * 256 + threadIdx.x;
  if (i < E) {
    int s = ei[i], d = ei[E + i];
    int pos = atomicAdd(&cursor[d], 1);
    csr_src[pos] = s;
  }
}

// one wave per dst node. Single fused pass, branchless load-hoisted accumulate:
// 16 edges per j-step, 8 float4 gathers in flight per lane before any waitcnt.
// Invalid edge slots contribute via weight=0 (address clamped to row 0).
__global__ __launch_bounds__(256) void k_agg(
    const int* __restrict__ csr_src, const int* __restrict__ offs,
    const float* __restrict__ a_src, const float* __restrict__ a_dst,
    const float* __restrict__ xh, const int* __restrict__ batch,
    const float* __restrict__ bias, float* __restrict__ pool_sum,
    int* __restrict__ pool_cnt, int N) {
  const int wid = (blockIdx.x * 256 + threadIdx.x) >> 6;
  const int lane = threadIdx.x & 63;
  if (wid >= N) return;
  const int n = wid;
  const int o0 = offs[n], deg = offs[n + 1] - o0;
  const float4 dv = ((const float4*)a_dst)[n];
  const int l16 = lane & 15, g = lane >> 4, h = l16 >> 2;
  const float4* __restrict__ xh4 = (const float4*)xh;

  float4 sm = make_float4(0.f, 0.f, 0.f, 0.f);
  float4 ac0 = make_float4(0.f, 0.f, 0.f, 0.f);
  float4 ac1 = make_float4(0.f, 0.f, 0.f, 0.f);

  for (int c0 = 0; c0 < deg; c0 += 64) {
    const int cl = min(64, deg - c0);
    int sj = 0;
    float4 w4 = make_float4(0.f, 0.f, 0.f, 0.f);
    if (lane < cl) {
      sj = csr_src[o0 + c0 + lane];
      float4 av = ((const float4*)a_src)[sj];
      w4.x = __expf(lrelu(av.x + dv.x, NS_ATT));
      w4.y = __expf(lrelu(av.y + dv.y, NS_ATT));
      w4.z = __expf(lrelu(av.z + dv.z, NS_ATT));
      w4.w = __expf(lrelu(av.w + dv.w, NS_ATT));
      sm.x += w4.x; sm.y += w4.y; sm.z += w4.z; sm.w += w4.w;
    }
    for (int j = 0; j < cl; j += 16) {
      int s[4];
      float wsel[4];
      float4 va[4], vb[4];
#pragma unroll
      for (int q = 0; q < 4; ++q) {
        const int ee = j + q * 4 + g;      // groups g=0..3, slots q=0..3 -> edges j..j+15
        const bool valid = ee < cl;
        const int es = ee & 63;
        const int ss = __shfl(sj, es);
        const float wx = __shfl(w4.x, es), wy = __shfl(w4.y, es);
        const float wz = __shfl(w4.z, es), ww = __shfl(w4.w, es);
        const float wv = (h == 0) ? wx : (h == 1) ? wy : (h == 2) ? wz : ww;
        wsel[q] = valid ? wv : 0.f;
        s[q] = valid ? ss : 0;
      }
#pragma unroll
      for (int q = 0; q < 4; ++q) {
        va[q] = xh4[(long)s[q] * 32 + l16 * 2];
        vb[q] = xh4[(long)s[q] * 32 + l16 * 2 + 1];
      }
#pragma unroll
      for (int q = 0; q < 4; ++q) {
        ac0.x = fmaf(wsel[q], va[q].x, ac0.x); ac0.y = fmaf(wsel[q], va[q].y, ac0.y);
        ac0.z = fmaf(wsel[q], va[q].z, ac0.z); ac0.w = fmaf(wsel[q], va[q].w, ac0.w);
        ac1.x = fmaf(wsel[q], vb[q].x, ac1.x); ac1.y = fmaf(wsel[q], vb[q].y, ac1.y);
        ac1.z = fmaf(wsel[q], vb[q].z, ac1.z); ac1.w = fmaf(wsel[q], vb[q].w, ac1.w);
      }
    }
  }

  // reduce denominator across all 64 lanes
#pragma unroll
  for (int m = 32; m >= 1; m >>= 1) {
    sm.x += __shfl_xor(sm.x, m);
    sm.y += __shfl_xor(sm.y, m);
    sm.z += __shfl_xor(sm.z, m);
    sm.w += __shfl_xor(sm.w, m);
  }
  // reduce accumulators across the 4 groups (bits 4,5)
#pragma unroll
  for (int m = 32; m >= 16; m >>= 1) {
    ac0.x += __shfl_xor(ac0.x, m); ac0.y += __shfl_xor(ac0.y, m);
    ac0.z += __shfl_xor(ac0.z, m); ac0.w += __shfl_xor(ac0.w, m);
    ac1.x += __shfl_xor(ac1.x, m); ac1.y += __shfl_xor(ac1.y, m);
    ac1.z += __shfl_xor(ac1.z, m); ac1.w += __shfl_xor(ac1.w, m);
  }

  const float sh = (h == 0) ? sm.x : (h == 1) ? sm.y : (h == 2) ? sm.z : sm.w;
  const float inv = 1.f / (sh + 1e-16f);
  // lane writes channels l16*8 + g*2, +1
  float r0, r1;
  if (g == 0)      { r0 = ac0.x; r1 = ac0.y; }
  else if (g == 1) { r0 = ac0.z; r1 = ac0.w; }
  else if (g == 2) { r0 = ac1.x; r1 = ac1.y; }
  else             { r0 = ac1.z; r1 = ac1.w; }
  const int ch = l16 * 8 + g * 2;
  r0 = lrelu(r0 * inv + bias[ch], NS_ACT);
  r1 = lrelu(r1 * inv + bias[ch + 1], NS_ACT);
  const int b = batch[n];
  atomicAdd(&pool_sum[b * HC + ch], r0);
  atomicAdd(&pool_sum[b * HC + ch + 1], r1);
  if (lane == 0) atomicAdd(&pool_cnt[b], 1);
}

__global__ void k_final(const float* __restrict__ pool_sum, const int* __restrict__ pool_cnt,
                        const float* __restrict__ lin_w, const float* __restrict__ lin_b,
                        float* __restrict__ out, int B) {
  int b = blockIdx.x;
  __shared__ float pl[HC];
  int t = threadIdx.x;
  float c = fmaxf((float)pool_cnt[b], 1.0f);
  pl[t] = pool_sum[b * HC + t] / c;
  __syncthreads();
  if (t < 10) {
    float a = lin_b[t];
    for (int k = 0; k < HC; ++k) a = fmaf(pl[k], lin_w[t * HC + k], a);
    out[b * 10 + t] = a;
  }
}

extern "C" void kernel_launch(void* const* d_in, const int* in_sizes, int n_in,
                              void* d_out, int out_size, void* d_ws, size_t ws_size,
                              hipStream_t stream) {
  const float* x = (const float*)d_in[0];
  const int* ei = (const int*)d_in[1];      // int64 in reference -> int32 on device
  const int* batch = (const int*)d_in[2];   // int64 in reference -> int32 on device
  const float* Wm = (const float*)d_in[4];
  const float* att_s = (const float*)d_in[5];
  const float* att_d = (const float*)d_in[6];
  const float* bias = (const float*)d_in[7];
  const float* lin_w = (const float*)d_in[8];
  const float* lin_b = (const float*)d_in[9];
  float* out = (float*)d_out;

  const int N = in_sizes[2];
  const int E = in_sizes[1] / 2;
  const int B = out_size / 10;
  const int NB = (N + 255) / 256;  // must be <= 1024 (N <= 262144)

  char* p = (char*)d_ws;
  auto carve = [&](size_t bytes) {
    void* r = (void*)p;
    p += (bytes + 255) & ~(size_t)255;
    return r;
  };
  float* xh = (float*)carve((size_t)N * HC * 4);
  float* a_src = (float*)carve((size_t)N * NHEAD * 4);
  float* a_dst = (float*)carve((size_t)N * NHEAD * 4);
  int* cnt = (int*)carve((size_t)N * 4);
  int* offs = (int*)carve((size_t)(N + 1) * 4);
  int* cursor = (int*)carve((size_t)N * 4);
  int* part = (int*)carve((size_t)(NB + 2) * 4);
  int* csr_src = (int*)carve((size_t)(N + (size_t)E) * 4);
  float* pool_sum = (float*)carve((size_t)B * HC * 4);
  int* pool_cnt = (int*)carve((size_t)B * 4);

  const int initN = (N > B * HC) ? N : B * HC;
  k_init<<<(initN + 255) / 256, 256, 0, stream>>>(cnt, pool_sum, pool_cnt, N, B);
  k_gemm<<<(N + 63) / 64, 256, 0, stream>>>(x, Wm, att_s, att_d, xh, a_src, a_dst, N);
  k_count<<<(E + 255) / 256, 256, 0, stream>>>(ei, cnt, E);
  k_scanA<<<NB, 256, 0, stream>>>(cnt, offs, part, N);
  k_scanB<<<1, 1024, 0, stream>>>(part, NB);
  k_scanC<<<(N + 256) / 256, 256, 0, stream>>>(offs, part, N, NB);
  k_selfloop<<<(N + 255) / 256, 256, 0, stream>>>(offs, cursor, csr_src, N);
  k_fill<<<(E + 255) / 256, 256, 0, stream>>>(ei, cursor, csr_src, E);
  k_agg<<<(N + 3) / 4, 256, 0, stream>>>(csr_src, offs, a_src, a_dst, xh, batch, bias,
                                         pool_sum, pool_cnt, N);
  k_final<<<B, 128, 0, stream>>>(pool_sum, pool_cnt, lin_w, lin_b, out, B);
}

// Round 5
// 913.738 us; speedup vs baseline: 1.0622x; 1.0622x over previous
//
#include <hip/hip_runtime.h>
#include <hip/hip_fp16.h>

#define HC 128
#define FIN 128
#define NHEAD 4
#define NS_ATT 0.2f
#define NS_ACT 0.01f

__device__ __forceinline__ float lrelu(float v, float s) { return v >= 0.f ? v : s * v; }

// init: count=1 (self-loop), zero pooling buffers
__global__ void k_init(int* __restrict__ cnt, float* __restrict__ pool_sum,
                       int* __restrict__ pool_cnt, int N, int B) {
  int i = blockIdx.x * 256 + threadIdx.x;
  if (i < N) cnt[i] = 1;
  if (i < B * HC) pool_sum[i] = 0.f;
  if (i < B) pool_cnt[i] = 0;
}

// xh = x @ W  (fp16 store for the gather path) + fused a_src/a_dst head-dot epilogue
__global__ __launch_bounds__(256) void k_gemm(
    const float* __restrict__ x, const float* __restrict__ Wm,
    const float* __restrict__ att_s, const float* __restrict__ att_d,
    __half* __restrict__ xh, float* __restrict__ a_src, float* __restrict__ a_dst,
    int N) {
  __shared__ __align__(16) float xs[8][FIN];
  const int tid = threadIdx.x, tx = tid & 127, ty = tid >> 7;
  const long base = (long)blockIdx.x * 64;
  float w[FIN];
#pragma unroll
  for (int k = 0; k < FIN; ++k) w[k] = Wm[k * HC + tx];
  const float asc = att_s[tx], adc = att_d[tx];
  for (int g = 0; g < 8; ++g) {
    const long r0 = base + g * 8;
#pragma unroll
    for (int q = 0; q < 4; ++q) {
      int idx = tid + q * 256;
      int lr = idx >> 7, col = idx & 127;
      long row = r0 + lr;
      xs[lr][col] = (row < N) ? x[row * FIN + col] : 0.f;
    }
    __syncthreads();
#pragma unroll
    for (int ii = 0; ii < 4; ++ii) {
      const int lr = 2 * ii + ty;
      const long row = r0 + lr;
      const float4* xr = (const float4*)xs[lr];
      float acc[4] = {0.f, 0.f, 0.f, 0.f};
#pragma unroll
      for (int k4 = 0; k4 < 32; ++k4) {
        float4 v = xr[k4];
        acc[k4 & 3] = fmaf(v.w, w[4 * k4 + 3],
                      fmaf(v.z, w[4 * k4 + 2],
                      fmaf(v.y, w[4 * k4 + 1],
                      fmaf(v.x, w[4 * k4 + 0], acc[k4 & 3]))));
      }
      float a = (acc[0] + acc[1]) + (acc[2] + acc[3]);
      if (row < N) {
        xh[row * HC + tx] = __float2half_rn(a);
        float ps = a * asc, pd = a * adc;
#pragma unroll
        for (int m = 16; m >= 1; m >>= 1) {
          ps += __shfl_xor(ps, m);
          pd += __shfl_xor(pd, m);
        }
        if ((tx & 31) == 0) {
          int h = tx >> 5;
          a_src[row * NHEAD + h] = ps;
          a_dst[row * NHEAD + h] = pd;
        }
      }
    }
    __syncthreads();
  }
}

__global__ void k_count(const int* __restrict__ ei, int* __restrict__ cnt, int E) {
  int i = blockIdx.x * 256 + threadIdx.x;
  if (i < E) atomicAdd(&cnt[ei[E + i]], 1);
}

__global__ void k_scanA(const int* __restrict__ cnt, int* __restrict__ offs,
                        int* __restrict__ part, int N) {
  __shared__ int s[256];
  int t = threadIdx.x, i = blockIdx.x * 256 + t;
  int v = (i < N) ? cnt[i] : 0;
  s[t] = v;
#pragma unroll
  for (int off = 1; off < 256; off <<= 1) {
    __syncthreads();
    int u = (t >= off) ? s[t - off] : 0;
    __syncthreads();
    s[t] += u;
  }
  if (i < N) offs[i] = s[t] - v;
  if (t == 255) part[blockIdx.x] = s[255];
}

__global__ void k_scanB(int* __restrict__ part, int NB) {
  __shared__ int s[1024];
  int t = threadIdx.x;
  int v = (t < NB) ? part[t] : 0;
  s[t] = v;
#pragma unroll
  for (int off = 1; off < 1024; off <<= 1) {
    __syncthreads();
    int u = (t >= off) ? s[t - off] : 0;
    __syncthreads();
    s[t] += u;
  }
  if (t < NB) part[t] = s[t] - v;
  if (t == 1023) part[NB] = s[1023];
}

__global__ void k_scanC(int* __restrict__ offs, const int* __restrict__ part, int N, int NB) {
  int i = blockIdx.x * 256 + threadIdx.x;
  if (i < N) offs[i] += part[i >> 8];
  else if (i == N) offs[N] = part[NB];
}

__global__ void k_selfloop(const int* __restrict__ offs, int* __restrict__ cursor,
                           int* __restrict__ csr_src, int N) {
  int i = blockIdx.x * 256 + threadIdx.x;
  if (i < N) {
    int o = offs[i];
    cursor[i] = o + 1;
    csr_src[o] = i;
  }
}

__global__ void k_fill(const int* __restrict__ ei, int* __restrict__ cursor,
                       int* __restrict__ csr_src, int E) {
  int i = blockIdx.x * 256 + threadIdx.x;
  if (i < E) {
    int s = ei[i], d = ei[E + i];
    int pos = atomicAdd(&cursor[d], 1);
    csr_src[pos] = s;
  }
}

// one wave per dst node. fp16 xh gather: per edge, 16 lanes x 16B (8 halves each).
// 16 edges per j-step, 4 uint4 gathers in flight per lane; invalid slots get weight 0
// with address clamped to node 0 (cache-hot).
__global__ __launch_bounds__(256) void k_agg(
    const int* __restrict__ csr_src, const int* __restrict__ offs,
    const float* __restrict__ a_src, const float* __restrict__ a_dst,
    const __half* __restrict__ xh, const int* __restrict__ batch,
    const float* __restrict__ bias, float* __restrict__ pool_sum,
    int* __restrict__ pool_cnt, int N) {
  const int wid = (blockIdx.x * 256 + threadIdx.x) >> 6;
  const int lane = threadIdx.x & 63;
  if (wid >= N) return;
  const int n = wid;
  const int o0 = offs[n], deg = offs[n + 1] - o0;
  const float4 dv = ((const float4*)a_dst)[n];
  const int l16 = lane & 15, g = lane >> 4, h = l16 >> 2;
  const uint4* __restrict__ xh16 = (const uint4*)xh;  // 16 uint4 per node row

  float4 sm = make_float4(0.f, 0.f, 0.f, 0.f);
  float acc[8] = {0.f, 0.f, 0.f, 0.f, 0.f, 0.f, 0.f, 0.f};

  for (int c0 = 0; c0 < deg; c0 += 64) {
    const int cl = min(64, deg - c0);
    int sj = 0;
    float4 w4 = make_float4(0.f, 0.f, 0.f, 0.f);
    if (lane < cl) {
      sj = csr_src[o0 + c0 + lane];
      float4 av = ((const float4*)a_src)[sj];
      w4.x = __expf(lrelu(av.x + dv.x, NS_ATT));
      w4.y = __expf(lrelu(av.y + dv.y, NS_ATT));
      w4.z = __expf(lrelu(av.z + dv.z, NS_ATT));
      w4.w = __expf(lrelu(av.w + dv.w, NS_ATT));
      sm.x += w4.x; sm.y += w4.y; sm.z += w4.z; sm.w += w4.w;
    }
    for (int j = 0; j < cl; j += 16) {
      int s[4];
      float wsel[4];
      uint4 u[4];
#pragma unroll
      for (int q = 0; q < 4; ++q) {
        const int ee = j + q * 4 + g;      // groups g=0..3, slots q=0..3 -> edges j..j+15
        const bool valid = ee < cl;
        const int es = ee & 63;
        const int ss = __shfl(sj, es);
        const float wx = __shfl(w4.x, es), wy = __shfl(w4.y, es);
        const float wz = __shfl(w4.z, es), ww = __shfl(w4.w, es);
        const float wv = (h == 0) ? wx : (h == 1) ? wy : (h == 2) ? wz : ww;
        wsel[q] = valid ? wv : 0.f;
        s[q] = valid ? ss : 0;
      }
#pragma unroll
      for (int q = 0; q < 4; ++q) {
        u[q] = xh16[(long)s[q] * 16 + l16];
      }
#pragma unroll
      for (int q = 0; q < 4; ++q) {
        const __half2* hp = (const __half2*)&u[q];
        const float2 f0 = __half22float2(hp[0]);
        const float2 f1 = __half22float2(hp[1]);
        const float2 f2 = __half22float2(hp[2]);
        const float2 f3 = __half22float2(hp[3]);
        acc[0] = fmaf(wsel[q], f0.x, acc[0]); acc[1] = fmaf(wsel[q], f0.y, acc[1]);
        acc[2] = fmaf(wsel[q], f1.x, acc[2]); acc[3] = fmaf(wsel[q], f1.y, acc[3]);
        acc[4] = fmaf(wsel[q], f2.x, acc[4]); acc[5] = fmaf(wsel[q], f2.y, acc[5]);
        acc[6] = fmaf(wsel[q], f3.x, acc[6]); acc[7] = fmaf(wsel[q], f3.y, acc[7]);
      }
    }
  }

  // reduce denominator across all 64 lanes
#pragma unroll
  for (int m = 32; m >= 1; m >>= 1) {
    sm.x += __shfl_xor(sm.x, m);
    sm.y += __shfl_xor(sm.y, m);
    sm.z += __shfl_xor(sm.z, m);
    sm.w += __shfl_xor(sm.w, m);
  }
  // reduce accumulators across the 4 groups (lane bits 4,5)
#pragma unroll
  for (int m = 32; m >= 16; m >>= 1) {
#pragma unroll
    for (int i = 0; i < 8; ++i) acc[i] += __shfl_xor(acc[i], m);
  }

  const float sh = (h == 0) ? sm.x : (h == 1) ? sm.y : (h == 2) ? sm.z : sm.w;
  const float inv = 1.f / (sh + 1e-16f);
  // lane (g,l16) writes channels l16*8 + 2g, +1 from its fully-reduced acc
  const int ch = l16 * 8 + g * 2;
  float r0 = lrelu(acc[2 * g] * inv + bias[ch], NS_ACT);
  float r1 = lrelu(acc[2 * g + 1] * inv + bias[ch + 1], NS_ACT);
  const int b = batch[n];
  atomicAdd(&pool_sum[b * HC + ch], r0);
  atomicAdd(&pool_sum[b * HC + ch + 1], r1);
  if (lane == 0) atomicAdd(&pool_cnt[b], 1);
}

__global__ void k_final(const float* __restrict__ pool_sum, const int* __restrict__ pool_cnt,
                        const float* __restrict__ lin_w, const float* __restrict__ lin_b,
                        float* __restrict__ out, int B) {
  int b = blockIdx.x;
  __shared__ float pl[HC];
  int t = threadIdx.x;
  float c = fmaxf((float)pool_cnt[b], 1.0f);
  pl[t] = pool_sum[b * HC + t] / c;
  __syncthreads();
  if (t < 10) {
    float a = lin_b[t];
    for (int k = 0; k < HC; ++k) a = fmaf(pl[k], lin_w[t * HC + k], a);
    out[b * 10 + t] = a;
  }
}

extern "C" void kernel_launch(void* const* d_in, const int* in_sizes, int n_in,
                              void* d_out, int out_size, void* d_ws, size_t ws_size,
                              hipStream_t stream) {
  const float* x = (const float*)d_in[0];
  const int* ei = (const int*)d_in[1];      // int64 in reference -> int32 on device
  const int* batch = (const int*)d_in[2];   // int64 in reference -> int32 on device
  const float* Wm = (const float*)d_in[4];
  const float* att_s = (const float*)d_in[5];
  const float* att_d = (const float*)d_in[6];
  const float* bias = (const float*)d_in[7];
  const float* lin_w = (const float*)d_in[8];
  const float* lin_b = (const float*)d_in[9];
  float* out = (float*)d_out;

  const int N = in_sizes[2];
  const int E = in_sizes[1] / 2;
  const int B = out_size / 10;
  const int NB = (N + 255) / 256;  // must be <= 1024 (N <= 262144)

  char* p = (char*)d_ws;
  auto carve = [&](size_t bytes) {
    void* r = (void*)p;
    p += (bytes + 255) & ~(size_t)255;
    return r;
  };
  __half* xh = (__half*)carve((size_t)N * HC * 2);
  float* a_src = (float*)carve((size_t)N * NHEAD * 4);
  float* a_dst = (float*)carve((size_t)N * NHEAD * 4);
  int* cnt = (int*)carve((size_t)N * 4);
  int* offs = (int*)carve((size_t)(N + 1) * 4);
  int* cursor = (int*)carve((size_t)N * 4);
  int* part = (int*)carve((size_t)(NB + 2) * 4);
  int* csr_src = (int*)carve((size_t)(N + (size_t)E) * 4);
  float* pool_sum = (float*)carve((size_t)B * HC * 4);
  int* pool_cnt = (int*)carve((size_t)B * 4);

  const int initN = (N > B * HC) ? N : B * HC;
  k_init<<<(initN + 255) / 256, 256, 0, stream>>>(cnt, pool_sum, pool_cnt, N, B);
  k_gemm<<<(N + 63) / 64, 256, 0, stream>>>(x, Wm, att_s, att_d, xh, a_src, a_dst, N);
  k_count<<<(E + 255) / 256, 256, 0, stream>>>(ei, cnt, E);
  k_scanA<<<NB, 256, 0, stream>>>(cnt, offs, part, N);
  k_scanB<<<1, 1024, 0, stream>>>(part, NB);
  k_scanC<<<(N + 256) / 256, 256, 0, stream>>>(offs, part, N, NB);
  k_selfloop<<<(N + 255) / 256, 256, 0, stream>>>(offs, cursor, csr_src, N);
  k_fill<<<(E + 255) / 256, 256, 0, stream>>>(ei, cursor, csr_src, E);
  k_agg<<<(N + 3) / 4, 256, 0, stream>>>(csr_src, offs, a_src, a_dst, xh, batch, bias,
                                         pool_sum, pool_cnt, N);
  k_final<<<B, 128, 0, stream>>>(pool_sum, pool_cnt, lin_w, lin_b, out, B);
}

// Round 6
// 470.033 us; speedup vs baseline: 2.0649x; 1.9440x over previous
//
#include <hip/hip_runtime.h>
#include <hip/hip_fp16.h>

#define HC 128
#define FIN 128
#define NHEAD 4
#define NS_ATT 0.2f
#define NS_ACT 0.01f

__device__ __forceinline__ float lrelu(float v, float s) { return v >= 0.f ? v : s * v; }

__device__ __forceinline__ int lowerb(const int* __restrict__ a, int n, int v) {
  int lo = 0, hi = n;
  while (lo < hi) {
    int m = (lo + hi) >> 1;
    if (a[m] < v) lo = m + 1; else hi = m;
  }
  return lo;
}

// init: count=1 (self-loop), zero pooling buffers
__global__ void k_init(int* __restrict__ cnt, float* __restrict__ pool_sum,
                       int* __restrict__ pool_cnt, int N, int B) {
  int i = blockIdx.x * 256 + threadIdx.x;
  if (i < N) cnt[i] = 1;
  if (i < B * HC) pool_sum[i] = 0.f;
  if (i < B) pool_cnt[i] = 0;
}

// xh = x @ W  (fp16 store for the gather path) + fused a_src/a_dst head-dot epilogue
__global__ __launch_bounds__(256) void k_gemm(
    const float* __restrict__ x, const float* __restrict__ Wm,
    const float* __restrict__ att_s, const float* __restrict__ att_d,
    __half* __restrict__ xh, float* __restrict__ a_src, float* __restrict__ a_dst,
    int N) {
  __shared__ __align__(16) float xs[8][FIN];
  const int tid = threadIdx.x, tx = tid & 127, ty = tid >> 7;
  const long base = (long)blockIdx.x * 64;
  float w[FIN];
#pragma unroll
  for (int k = 0; k < FIN; ++k) w[k] = Wm[k * HC + tx];
  const float asc = att_s[tx], adc = att_d[tx];
  for (int g = 0; g < 8; ++g) {
    const long r0 = base + g * 8;
#pragma unroll
    for (int q = 0; q < 4; ++q) {
      int idx = tid + q * 256;
      int lr = idx >> 7, col = idx & 127;
      long row = r0 + lr;
      xs[lr][col] = (row < N) ? x[row * FIN + col] : 0.f;
    }
    __syncthreads();
#pragma unroll
    for (int ii = 0; ii < 4; ++ii) {
      const int lr = 2 * ii + ty;
      const long row = r0 + lr;
      const float4* xr = (const float4*)xs[lr];
      float acc[4] = {0.f, 0.f, 0.f, 0.f};
#pragma unroll
      for (int k4 = 0; k4 < 32; ++k4) {
        float4 v = xr[k4];
        acc[k4 & 3] = fmaf(v.w, w[4 * k4 + 3],
                      fmaf(v.z, w[4 * k4 + 2],
                      fmaf(v.y, w[4 * k4 + 1],
                      fmaf(v.x, w[4 * k4 + 0], acc[k4 & 3]))));
      }
      float a = (acc[0] + acc[1]) + (acc[2] + acc[3]);
      if (row < N) {
        xh[row * HC + tx] = __float2half_rn(a);
        float ps = a * asc, pd = a * adc;
#pragma unroll
        for (int m = 16; m >= 1; m >>= 1) {
          ps += __shfl_xor(ps, m);
          pd += __shfl_xor(pd, m);
        }
        if ((tx & 31) == 0) {
          int h = tx >> 5;
          a_src[row * NHEAD + h] = ps;
          a_dst[row * NHEAD + h] = pd;
        }
      }
    }
    __syncthreads();
  }
}

__global__ void k_count(const int* __restrict__ ei, int* __restrict__ cnt, int E) {
  int i = blockIdx.x * 256 + threadIdx.x;
  if (i < E) atomicAdd(&cnt[ei[E + i]], 1);
}

__global__ void k_scanA(const int* __restrict__ cnt, int* __restrict__ offs,
                        int* __restrict__ part, int N) {
  __shared__ int s[256];
  int t = threadIdx.x, i = blockIdx.x * 256 + t;
  int v = (i < N) ? cnt[i] : 0;
  s[t] = v;
#pragma unroll
  for (int off = 1; off < 256; off <<= 1) {
    __syncthreads();
    int u = (t >= off) ? s[t - off] : 0;
    __syncthreads();
    s[t] += u;
  }
  if (i < N) offs[i] = s[t] - v;
  if (t == 255) part[blockIdx.x] = s[255];
}

__global__ void k_scanB(int* __restrict__ part, int NB) {
  __shared__ int s[1024];
  int t = threadIdx.x;
  int v = (t < NB) ? part[t] : 0;
  s[t] = v;
#pragma unroll
  for (int off = 1; off < 1024; off <<= 1) {
    __syncthreads();
    int u = (t >= off) ? s[t - off] : 0;
    __syncthreads();
    s[t] += u;
  }
  if (t < NB) part[t] = s[t] - v;
  if (t == 1023) part[NB] = s[1023];
}

__global__ void k_scanC(int* __restrict__ offs, const int* __restrict__ part, int N, int NB) {
  int i = blockIdx.x * 256 + threadIdx.x;
  if (i < N) offs[i] += part[i >> 8];
  else if (i == N) offs[N] = part[NB];
}

__global__ void k_selfloop(const int* __restrict__ offs, int* __restrict__ cursor,
                           int* __restrict__ csr_src, int N) {
  int i = blockIdx.x * 256 + threadIdx.x;
  if (i < N) {
    int o = offs[i];
    cursor[i] = o + 1;
    csr_src[o] = i;
  }
}

__global__ void k_fill(const int* __restrict__ ei, int* __restrict__ cursor,
                       int* __restrict__ csr_src, int E) {
  int i = blockIdx.x * 256 + threadIdx.x;
  if (i < E) {
    int s = ei[i], d = ei[E + i];
    int pos = atomicAdd(&cursor[d], 1);
    csr_src[pos] = s;
  }
}

// one wave per dst node. fp16 xh gather; 16 edges per j-step, 4 uint4 gathers in
// flight per lane; invalid slots get weight 0 (address clamped to node 0).
// NO atomics: per-node result row is plain-stored to xout (fp16).
__global__ __launch_bounds__(256) void k_agg(
    const int* __restrict__ csr_src, const int* __restrict__ offs,
    const float* __restrict__ a_src, const float* __restrict__ a_dst,
    const __half* __restrict__ xh, const float* __restrict__ bias,
    __half* __restrict__ xout, int N) {
  const int wid = (blockIdx.x * 256 + threadIdx.x) >> 6;
  const int lane = threadIdx.x & 63;
  if (wid >= N) return;
  const int n = wid;
  const int o0 = offs[n], deg = offs[n + 1] - o0;
  const float4 dv = ((const float4*)a_dst)[n];
  const int l16 = lane & 15, g = lane >> 4, h = l16 >> 2;
  const uint4* __restrict__ xh16 = (const uint4*)xh;  // 16 uint4 per node row

  float4 sm = make_float4(0.f, 0.f, 0.f, 0.f);
  float acc[8] = {0.f, 0.f, 0.f, 0.f, 0.f, 0.f, 0.f, 0.f};

  for (int c0 = 0; c0 < deg; c0 += 64) {
    const int cl = min(64, deg - c0);
    int sj = 0;
    float4 w4 = make_float4(0.f, 0.f, 0.f, 0.f);
    if (lane < cl) {
      sj = csr_src[o0 + c0 + lane];
      float4 av = ((const float4*)a_src)[sj];
      w4.x = __expf(lrelu(av.x + dv.x, NS_ATT));
      w4.y = __expf(lrelu(av.y + dv.y, NS_ATT));
      w4.z = __expf(lrelu(av.z + dv.z, NS_ATT));
      w4.w = __expf(lrelu(av.w + dv.w, NS_ATT));
      sm.x += w4.x; sm.y += w4.y; sm.z += w4.z; sm.w += w4.w;
    }
    for (int j = 0; j < cl; j += 16) {
      int s[4];
      float wsel[4];
      uint4 u[4];
#pragma unroll
      for (int q = 0; q < 4; ++q) {
        const int ee = j + q * 4 + g;      // groups g=0..3, slots q=0..3 -> edges j..j+15
        const bool valid = ee < cl;
        const int es = ee & 63;
        const int ss = __shfl(sj, es);
        const float wx = __shfl(w4.x, es), wy = __shfl(w4.y, es);
        const float wz = __shfl(w4.z, es), ww = __shfl(w4.w, es);
        const float wv = (h == 0) ? wx : (h == 1) ? wy : (h == 2) ? wz : ww;
        wsel[q] = valid ? wv : 0.f;
        s[q] = valid ? ss : 0;
      }
#pragma unroll
      for (int q = 0; q < 4; ++q) {
        u[q] = xh16[(long)s[q] * 16 + l16];
      }
#pragma unroll
      for (int q = 0; q < 4; ++q) {
        const __half2* hp = (const __half2*)&u[q];
        const float2 f0 = __half22float2(hp[0]);
        const float2 f1 = __half22float2(hp[1]);
        const float2 f2 = __half22float2(hp[2]);
        const float2 f3 = __half22float2(hp[3]);
        acc[0] = fmaf(wsel[q], f0.x, acc[0]); acc[1] = fmaf(wsel[q], f0.y, acc[1]);
        acc[2] = fmaf(wsel[q], f1.x, acc[2]); acc[3] = fmaf(wsel[q], f1.y, acc[3]);
        acc[4] = fmaf(wsel[q], f2.x, acc[4]); acc[5] = fmaf(wsel[q], f2.y, acc[5]);
        acc[6] = fmaf(wsel[q], f3.x, acc[6]); acc[7] = fmaf(wsel[q], f3.y, acc[7]);
      }
    }
  }

  // reduce denominator across all 64 lanes
#pragma unroll
  for (int m = 32; m >= 1; m >>= 1) {
    sm.x += __shfl_xor(sm.x, m);
    sm.y += __shfl_xor(sm.y, m);
    sm.z += __shfl_xor(sm.z, m);
    sm.w += __shfl_xor(sm.w, m);
  }
  // reduce accumulators across the 4 groups (lane bits 4,5)
#pragma unroll
  for (int m = 32; m >= 16; m >>= 1) {
#pragma unroll
    for (int i = 0; i < 8; ++i) acc[i] += __shfl_xor(acc[i], m);
  }

  const float sh = (h == 0) ? sm.x : (h == 1) ? sm.y : (h == 2) ? sm.z : sm.w;
  const float inv = 1.f / (sh + 1e-16f);
  // lane (g,l16) owns channels ch = l16*8 + 2g, +1
  const int ch = l16 * 8 + g * 2;
  float r0 = lrelu(acc[2 * g] * inv + bias[ch], NS_ACT);
  float r1 = lrelu(acc[2 * g + 1] * inv + bias[ch + 1], NS_ACT);
  ((__half2*)(xout + (long)n * HC))[ch >> 1] = __floats2half2_rn(r0, r1);
}

// segmented mean-pool over sorted batch. grid = (B, 4): 4 blocks split each
// graph's row range; per-block LDS reduce -> 128 atomics (65k total).
__global__ __launch_bounds__(256) void k_pool(
    const __half* __restrict__ xout, const int* __restrict__ batch,
    float* __restrict__ pool_sum, int* __restrict__ pool_cnt, int N) {
  const int b = blockIdx.x, q = blockIdx.y, t = threadIdx.x;
  const int lo = lowerb(batch, N, b);
  const int hi = lowerb(batch, N, b + 1);
  const int cnt = hi - lo;
  if (q == 0 && t == 0) pool_cnt[b] = cnt;
  const int qlen = (cnt + 3) >> 2;
  const int qlo = lo + q * qlen;
  const int qhi = min(qlo + qlen, hi);

  const int c2 = t & 63;     // half2 channel index (covers 128 channels)
  const int rs = t >> 6;     // 4 row streams
  const __half2* __restrict__ xo2 = (const __half2*)xout;
  float ax = 0.f, ay = 0.f, bx2 = 0.f, by2 = 0.f;
  int r = qlo + rs;
  for (; r + 4 < qhi; r += 8) {
    float2 f0 = __half22float2(xo2[(long)r * 64 + c2]);
    float2 f1 = __half22float2(xo2[(long)(r + 4) * 64 + c2]);
    ax += f0.x; ay += f0.y; bx2 += f1.x; by2 += f1.y;
  }
  for (; r < qhi; r += 4) {
    float2 f0 = __half22float2(xo2[(long)r * 64 + c2]);
    ax += f0.x; ay += f0.y;
  }
  __shared__ float2 sp[256];
  sp[t] = make_float2(ax + bx2, ay + by2);
  __syncthreads();
  if (t < 64) {
    float2 s0 = sp[t], s1 = sp[t + 64], s2 = sp[t + 128], s3 = sp[t + 192];
    float vx = (s0.x + s1.x) + (s2.x + s3.x);
    float vy = (s0.y + s1.y) + (s2.y + s3.y);
    atomicAdd(&pool_sum[b * HC + 2 * t], vx);
    atomicAdd(&pool_sum[b * HC + 2 * t + 1], vy);
  }
}

__global__ void k_final(const float* __restrict__ pool_sum, const int* __restrict__ pool_cnt,
                        const float* __restrict__ lin_w, const float* __restrict__ lin_b,
                        float* __restrict__ out, int B) {
  int b = blockIdx.x;
  __shared__ float pl[HC];
  int t = threadIdx.x;
  float c = fmaxf((float)pool_cnt[b], 1.0f);
  pl[t] = pool_sum[b * HC + t] / c;
  __syncthreads();
  if (t < 10) {
    float a = lin_b[t];
    for (int k = 0; k < HC; ++k) a = fmaf(pl[k], lin_w[t * HC + k], a);
    out[b * 10 + t] = a;
  }
}

extern "C" void kernel_launch(void* const* d_in, const int* in_sizes, int n_in,
                              void* d_out, int out_size, void* d_ws, size_t ws_size,
                              hipStream_t stream) {
  const float* x = (const float*)d_in[0];
  const int* ei = (const int*)d_in[1];      // int64 in reference -> int32 on device
  const int* batch = (const int*)d_in[2];   // int64 in reference -> int32 on device
  const float* Wm = (const float*)d_in[4];
  const float* att_s = (const float*)d_in[5];
  const float* att_d = (const float*)d_in[6];
  const float* bias = (const float*)d_in[7];
  const float* lin_w = (const float*)d_in[8];
  const float* lin_b = (const float*)d_in[9];
  float* out = (float*)d_out;

  const int N = in_sizes[2];
  const int E = in_sizes[1] / 2;
  const int B = out_size / 10;
  const int NB = (N + 255) / 256;  // must be <= 1024 (N <= 262144)

  char* p = (char*)d_ws;
  auto carve = [&](size_t bytes) {
    void* r = (void*)p;
    p += (bytes + 255) & ~(size_t)255;
    return r;
  };
  __half* xh = (__half*)carve((size_t)N * HC * 2);
  __half* xout = (__half*)carve((size_t)N * HC * 2);
  float* a_src = (float*)carve((size_t)N * NHEAD * 4);
  float* a_dst = (float*)carve((size_t)N * NHEAD * 4);
  int* cnt = (int*)carve((size_t)N * 4);
  int* offs = (int*)carve((size_t)(N + 1) * 4);
  int* cursor = (int*)carve((size_t)N * 4);
  int* part = (int*)carve((size_t)(NB + 2) * 4);
  int* csr_src = (int*)carve((size_t)(N + (size_t)E) * 4);
  float* pool_sum = (float*)carve((size_t)B * HC * 4);
  int* pool_cnt = (int*)carve((size_t)B * 4);

  const int initN = (N > B * HC) ? N : B * HC;
  k_init<<<(initN + 255) / 256, 256, 0, stream>>>(cnt, pool_sum, pool_cnt, N, B);
  k_gemm<<<(N + 63) / 64, 256, 0, stream>>>(x, Wm, att_s, att_d, xh, a_src, a_dst, N);
  k_count<<<(E + 255) / 256, 256, 0, stream>>>(ei, cnt, E);
  k_scanA<<<NB, 256, 0, stream>>>(cnt, offs, part, N);
  k_scanB<<<1, 1024, 0, stream>>>(part, NB);
  k_scanC<<<(N + 256) / 256, 256, 0, stream>>>(offs, part, N, NB);
  k_selfloop<<<(N + 255) / 256, 256, 0, stream>>>(offs, cursor, csr_src, N);
  k_fill<<<(E + 255) / 256, 256, 0, stream>>>(ei, cursor, csr_src, E);
  k_agg<<<(N + 3) / 4, 256, 0, stream>>>(csr_src, offs, a_src, a_dst, xh, bias, xout, N);
  k_pool<<<dim3(B, 4), 256, 0, stream>>>(xout, batch, pool_sum, pool_cnt, N);
  k_final<<<B, 128, 0, stream>>>(pool_sum, pool_cnt, lin_w, lin_b, out, B);
}

// Round 7
// 355.896 us; speedup vs baseline: 2.7271x; 1.3207x over previous
//
#include <hip/hip_runtime.h>
#include <hip/hip_fp16.h>

#define HC 128
#define FIN 128
#define NHEAD 4
#define NS_ATT 0.2f
#define NS_ACT 0.01f

typedef _Float16 half8 __attribute__((ext_vector_type(8)));
typedef float f32x4 __attribute__((ext_vector_type(4)));

__device__ __forceinline__ float lrelu(float v, float s) { return v >= 0.f ? v : s * v; }

__device__ __forceinline__ int lowerb(const int* __restrict__ a, int n, int v) {
  int lo = 0, hi = n;
  while (lo < hi) {
    int m = (lo + hi) >> 1;
    if (a[m] < v) lo = m + 1; else hi = m;
  }
  return lo;
}

// init: count=1 (self-loop), zero pooling buffers
__global__ void k_init(int* __restrict__ cnt, float* __restrict__ pool_sum,
                       int* __restrict__ pool_cnt, int N, int B) {
  int i = blockIdx.x * 256 + threadIdx.x;
  if (i < N) cnt[i] = 1;
  if (i < B * HC) pool_sum[i] = 0.f;
  if (i < B) pool_cnt[i] = 0;
}

// Pre-swizzle W (fp32 [128][128]) into fp16 MFMA B-fragments, appending
// W@A columns (per-head att_src/att_dst dots) as N-tile 8 (cols 128..135).
// grid = 9 (nt), 256 threads = kt (t>>6) x lane (t&63).
// B-frag layout for mfma_f32_16x16x32_f16: lane holds col = l&15,
// k = kt*32 + (l>>4)*8 + j, j=0..7 contiguous.
__global__ void k_wprep(const float* __restrict__ W, const float* __restrict__ att_s,
                        const float* __restrict__ att_d, _Float16* __restrict__ Wh) {
  const int nt = blockIdx.x, t = threadIdx.x;
  const int kt = t >> 6, l = t & 63;
  const int c = nt * 16 + (l & 15);
  const int kbase = kt * 32 + (l >> 4) * 8;
  half8 v8;
#pragma unroll
  for (int j = 0; j < 8; ++j) {
    const int k = kbase + j;
    float v = 0.f;
    if (c < 128) {
      v = W[k * HC + c];
    } else if (c < 132) {
      const int h = c - 128;
      for (int cc = 0; cc < 32; ++cc) v += W[k * HC + h * 32 + cc] * att_s[h * 32 + cc];
    } else if (c < 136) {
      const int h = c - 132;
      for (int cc = 0; cc < 32; ++cc) v += W[k * HC + h * 32 + cc] * att_d[h * 32 + cc];
    }
    v8[j] = (_Float16)v;
  }
  ((half8*)Wh)[(nt * 4 + kt) * 64 + l] = v8;
}

// MFMA GEMM: xh[N][128] (fp16) = x @ W, plus a_src/a_dst via the appended WA tile.
// One wave per 16 rows, 4 waves/block, no LDS/barriers.
__global__ __launch_bounds__(256) void k_xw(
    const float* __restrict__ x, const _Float16* __restrict__ Wh,
    _Float16* __restrict__ xh, float* __restrict__ a_src, float* __restrict__ a_dst,
    int N) {
  const int wv = threadIdx.x >> 6, l = threadIdx.x & 63;
  const int r0 = blockIdx.x * 64 + wv * 16;
  if (r0 >= N) return;
  const int row_a = r0 + (l & 15);
  const long arow = (long)min(row_a, N - 1) * FIN;
  const int kg = (l >> 4) * 8;

  // A fragments for kt=0..3 (row = l&15, k = kt*32 + kg + j)
  half8 afr[4];
#pragma unroll
  for (int kt = 0; kt < 4; ++kt) {
    const float4 p0 = *(const float4*)(x + arow + kt * 32 + kg);
    const float4 p1 = *(const float4*)(x + arow + kt * 32 + kg + 4);
    afr[kt][0] = (_Float16)p0.x; afr[kt][1] = (_Float16)p0.y;
    afr[kt][2] = (_Float16)p0.z; afr[kt][3] = (_Float16)p0.w;
    afr[kt][4] = (_Float16)p1.x; afr[kt][5] = (_Float16)p1.y;
    afr[kt][6] = (_Float16)p1.z; afr[kt][7] = (_Float16)p1.w;
  }

  const half8* __restrict__ Wh8 = (const half8*)Wh;
  const int rbase = r0 + (l >> 4) * 4;
  const int cc = l & 15;
#pragma unroll
  for (int nt = 0; nt < 9; ++nt) {
    half8 b0 = Wh8[(nt * 4 + 0) * 64 + l];
    half8 b1 = Wh8[(nt * 4 + 1) * 64 + l];
    half8 b2 = Wh8[(nt * 4 + 2) * 64 + l];
    half8 b3 = Wh8[(nt * 4 + 3) * 64 + l];
    f32x4 acc = {0.f, 0.f, 0.f, 0.f};
    acc = __builtin_amdgcn_mfma_f32_16x16x32_f16(afr[0], b0, acc, 0, 0, 0);
    acc = __builtin_amdgcn_mfma_f32_16x16x32_f16(afr[1], b1, acc, 0, 0, 0);
    acc = __builtin_amdgcn_mfma_f32_16x16x32_f16(afr[2], b2, acc, 0, 0, 0);
    acc = __builtin_amdgcn_mfma_f32_16x16x32_f16(afr[3], b3, acc, 0, 0, 0);
    if (nt < 8) {
      const int col = nt * 16 + cc;
#pragma unroll
      for (int r = 0; r < 4; ++r) {
        const int row = rbase + r;
        if (row < N) xh[(long)row * HC + col] = (_Float16)acc[r];
      }
    } else if (cc < 8) {
      float* __restrict__ dst = (cc < 4) ? a_src : a_dst;
      const int h = cc & 3;
#pragma unroll
      for (int r = 0; r < 4; ++r) {
        const int row = rbase + r;
        if (row < N) dst[row * NHEAD + h] = acc[r];
      }
    }
  }
}

__global__ void k_count(const int* __restrict__ ei, int* __restrict__ cnt, int E) {
  int i = blockIdx.x * 256 + threadIdx.x;
  if (i < E) atomicAdd(&cnt[ei[E + i]], 1);
}

__global__ void k_scanA(const int* __restrict__ cnt, int* __restrict__ offs,
                        int* __restrict__ part, int N) {
  __shared__ int s[256];
  int t = threadIdx.x, i = blockIdx.x * 256 + t;
  int v = (i < N) ? cnt[i] : 0;
  s[t] = v;
#pragma unroll
  for (int off = 1; off < 256; off <<= 1) {
    __syncthreads();
    int u = (t >= off) ? s[t - off] : 0;
    __syncthreads();
    s[t] += u;
  }
  if (i < N) offs[i] = s[t] - v;
  if (t == 255) part[blockIdx.x] = s[255];
}

__global__ void k_scanB(int* __restrict__ part, int NB) {
  __shared__ int s[1024];
  int t = threadIdx.x;
  int v = (t < NB) ? part[t] : 0;
  s[t] = v;
#pragma unroll
  for (int off = 1; off < 1024; off <<= 1) {
    __syncthreads();
    int u = (t >= off) ? s[t - off] : 0;
    __syncthreads();
    s[t] += u;
  }
  if (t < NB) part[t] = s[t] - v;
  if (t == 1023) part[NB] = s[1023];
}

__global__ void k_scanC(int* __restrict__ offs, const int* __restrict__ part, int N, int NB) {
  int i = blockIdx.x * 256 + threadIdx.x;
  if (i < N) offs[i] += part[i >> 8];
  else if (i == N) offs[N] = part[NB];
}

__global__ void k_selfloop(const int* __restrict__ offs, int* __restrict__ cursor,
                           int* __restrict__ csr_src, int N) {
  int i = blockIdx.x * 256 + threadIdx.x;
  if (i < N) {
    int o = offs[i];
    cursor[i] = o + 1;
    csr_src[o] = i;
  }
}

__global__ void k_fill(const int* __restrict__ ei, int* __restrict__ cursor,
                       int* __restrict__ csr_src, int E) {
  int i = blockIdx.x * 256 + threadIdx.x;
  if (i < E) {
    int s = ei[i], d = ei[E + i];
    int pos = atomicAdd(&cursor[d], 1);
    csr_src[pos] = s;
  }
}

// one wave per dst node. fp16 xh gather; 16 edges per j-step, 4 uint4 gathers in
// flight per lane; invalid slots get weight 0 (address clamped to node 0).
// NO atomics: per-node result row is plain-stored to xout (fp16).
__global__ __launch_bounds__(256) void k_agg(
    const int* __restrict__ csr_src, const int* __restrict__ offs,
    const float* __restrict__ a_src, const float* __restrict__ a_dst,
    const __half* __restrict__ xh, const float* __restrict__ bias,
    __half* __restrict__ xout, int N) {
  const int wid = (blockIdx.x * 256 + threadIdx.x) >> 6;
  const int lane = threadIdx.x & 63;
  if (wid >= N) return;
  const int n = wid;
  const int o0 = offs[n], deg = offs[n + 1] - o0;
  const float4 dv = ((const float4*)a_dst)[n];
  const int l16 = lane & 15, g = lane >> 4, h = l16 >> 2;
  const uint4* __restrict__ xh16 = (const uint4*)xh;  // 16 uint4 per node row

  float4 sm = make_float4(0.f, 0.f, 0.f, 0.f);
  float acc[8] = {0.f, 0.f, 0.f, 0.f, 0.f, 0.f, 0.f, 0.f};

  for (int c0 = 0; c0 < deg; c0 += 64) {
    const int cl = min(64, deg - c0);
    int sj = 0;
    float4 w4 = make_float4(0.f, 0.f, 0.f, 0.f);
    if (lane < cl) {
      sj = csr_src[o0 + c0 + lane];
      float4 av = ((const float4*)a_src)[sj];
      w4.x = __expf(lrelu(av.x + dv.x, NS_ATT));
      w4.y = __expf(lrelu(av.y + dv.y, NS_ATT));
      w4.z = __expf(lrelu(av.z + dv.z, NS_ATT));
      w4.w = __expf(lrelu(av.w + dv.w, NS_ATT));
      sm.x += w4.x; sm.y += w4.y; sm.z += w4.z; sm.w += w4.w;
    }
    for (int j = 0; j < cl; j += 16) {
      int s[4];
      float wsel[4];
      uint4 u[4];
#pragma unroll
      for (int q = 0; q < 4; ++q) {
        const int ee = j + q * 4 + g;      // groups g=0..3, slots q=0..3 -> edges j..j+15
        const bool valid = ee < cl;
        const int es = ee & 63;
        const int ss = __shfl(sj, es);
        const float wx = __shfl(w4.x, es), wy = __shfl(w4.y, es);
        const float wz = __shfl(w4.z, es), ww = __shfl(w4.w, es);
        const float wv = (h == 0) ? wx : (h == 1) ? wy : (h == 2) ? wz : ww;
        wsel[q] = valid ? wv : 0.f;
        s[q] = valid ? ss : 0;
      }
#pragma unroll
      for (int q = 0; q < 4; ++q) {
        u[q] = xh16[(long)s[q] * 16 + l16];
      }
#pragma unroll
      for (int q = 0; q < 4; ++q) {
        const __half2* hp = (const __half2*)&u[q];
        const float2 f0 = __half22float2(hp[0]);
        const float2 f1 = __half22float2(hp[1]);
        const float2 f2 = __half22float2(hp[2]);
        const float2 f3 = __half22float2(hp[3]);
        acc[0] = fmaf(wsel[q], f0.x, acc[0]); acc[1] = fmaf(wsel[q], f0.y, acc[1]);
        acc[2] = fmaf(wsel[q], f1.x, acc[2]); acc[3] = fmaf(wsel[q], f1.y, acc[3]);
        acc[4] = fmaf(wsel[q], f2.x, acc[4]); acc[5] = fmaf(wsel[q], f2.y, acc[5]);
        acc[6] = fmaf(wsel[q], f3.x, acc[6]); acc[7] = fmaf(wsel[q], f3.y, acc[7]);
      }
    }
  }

  // reduce denominator across all 64 lanes
#pragma unroll
  for (int m = 32; m >= 1; m >>= 1) {
    sm.x += __shfl_xor(sm.x, m);
    sm.y += __shfl_xor(sm.y, m);
    sm.z += __shfl_xor(sm.z, m);
    sm.w += __shfl_xor(sm.w, m);
  }
  // reduce accumulators across the 4 groups (lane bits 4,5)
#pragma unroll
  for (int m = 32; m >= 16; m >>= 1) {
#pragma unroll
    for (int i = 0; i < 8; ++i) acc[i] += __shfl_xor(acc[i], m);
  }

  const float sh = (h == 0) ? sm.x : (h == 1) ? sm.y : (h == 2) ? sm.z : sm.w;
  const float inv = 1.f / (sh + 1e-16f);
  // lane (g,l16) owns channels ch = l16*8 + 2g, +1
  const int ch = l16 * 8 + g * 2;
  float r0 = lrelu(acc[2 * g] * inv + bias[ch], NS_ACT);
  float r1 = lrelu(acc[2 * g + 1] * inv + bias[ch + 1], NS_ACT);
  ((__half2*)(xout + (long)n * HC))[ch >> 1] = __floats2half2_rn(r0, r1);
}

// segmented mean-pool over sorted batch. grid = (B, 4): 4 blocks split each
// graph's row range; per-block LDS reduce -> 128 atomics (65k total).
__global__ __launch_bounds__(256) void k_pool(
    const __half* __restrict__ xout, const int* __restrict__ batch,
    float* __restrict__ pool_sum, int* __restrict__ pool_cnt, int N) {
  const int b = blockIdx.x, q = blockIdx.y, t = threadIdx.x;
  const int lo = lowerb(batch, N, b);
  const int hi = lowerb(batch, N, b + 1);
  const int cnt = hi - lo;
  if (q == 0 && t == 0) pool_cnt[b] = cnt;
  const int qlen = (cnt + 3) >> 2;
  const int qlo = lo + q * qlen;
  const int qhi = min(qlo + qlen, hi);

  const int c2 = t & 63;     // half2 channel index (covers 128 channels)
  const int rs = t >> 6;     // 4 row streams
  const __half2* __restrict__ xo2 = (const __half2*)xout;
  float ax = 0.f, ay = 0.f, bx2 = 0.f, by2 = 0.f;
  int r = qlo + rs;
  for (; r + 4 < qhi; r += 8) {
    float2 f0 = __half22float2(xo2[(long)r * 64 + c2]);
    float2 f1 = __half22float2(xo2[(long)(r + 4) * 64 + c2]);
    ax += f0.x; ay += f0.y; bx2 += f1.x; by2 += f1.y;
  }
  for (; r < qhi; r += 4) {
    float2 f0 = __half22float2(xo2[(long)r * 64 + c2]);
    ax += f0.x; ay += f0.y;
  }
  __shared__ float2 sp[256];
  sp[t] = make_float2(ax + bx2, ay + by2);
  __syncthreads();
  if (t < 64) {
    float2 s0 = sp[t], s1 = sp[t + 64], s2 = sp[t + 128], s3 = sp[t + 192];
    float vx = (s0.x + s1.x) + (s2.x + s3.x);
    float vy = (s0.y + s1.y) + (s2.y + s3.y);
    atomicAdd(&pool_sum[b * HC + 2 * t], vx);
    atomicAdd(&pool_sum[b * HC + 2 * t + 1], vy);
  }
}

__global__ void k_final(const float* __restrict__ pool_sum, const int* __restrict__ pool_cnt,
                        const float* __restrict__ lin_w, const float* __restrict__ lin_b,
                        float* __restrict__ out, int B) {
  int b = blockIdx.x;
  __shared__ float pl[HC];
  int t = threadIdx.x;
  float c = fmaxf((float)pool_cnt[b], 1.0f);
  pl[t] = pool_sum[b * HC + t] / c;
  __syncthreads();
  if (t < 10) {
    float a = lin_b[t];
    for (int k = 0; k < HC; ++k) a = fmaf(pl[k], lin_w[t * HC + k], a);
    out[b * 10 + t] = a;
  }
}

extern "C" void kernel_launch(void* const* d_in, const int* in_sizes, int n_in,
                              void* d_out, int out_size, void* d_ws, size_t ws_size,
                              hipStream_t stream) {
  const float* x = (const float*)d_in[0];
  const int* ei = (const int*)d_in[1];      // int64 in reference -> int32 on device
  const int* batch = (const int*)d_in[2];   // int64 in reference -> int32 on device
  const float* Wm = (const float*)d_in[4];
  const float* att_s = (const float*)d_in[5];
  const float* att_d = (const float*)d_in[6];
  const float* bias = (const float*)d_in[7];
  const float* lin_w = (const float*)d_in[8];
  const float* lin_b = (const float*)d_in[9];
  float* out = (float*)d_out;

  const int N = in_sizes[2];
  const int E = in_sizes[1] / 2;
  const int B = out_size / 10;
  const int NB = (N + 255) / 256;  // must be <= 1024 (N <= 262144)

  char* p = (char*)d_ws;
  auto carve = [&](size_t bytes) {
    void* r = (void*)p;
    p += (bytes + 255) & ~(size_t)255;
    return r;
  };
  __half* xh = (__half*)carve((size_t)N * HC * 2);
  __half* xout = (__half*)carve((size_t)N * HC * 2);
  float* a_src = (float*)carve((size_t)N * NHEAD * 4);
  float* a_dst = (float*)carve((size_t)N * NHEAD * 4);
  int* cnt = (int*)carve((size_t)N * 4);
  int* offs = (int*)carve((size_t)(N + 1) * 4);
  int* cursor = (int*)carve((size_t)N * 4);
  int* part = (int*)carve((size_t)(NB + 2) * 4);
  int* csr_src = (int*)carve((size_t)(N + (size_t)E) * 4);
  float* pool_sum = (float*)carve((size_t)B * HC * 4);
  int* pool_cnt = (int*)carve((size_t)B * 4);
  _Float16* Wh = (_Float16*)carve((size_t)9 * 4 * 64 * 8 * 2);  // B-fragments (36 KB)

  const int initN = (N > B * HC) ? N : B * HC;
  k_init<<<(initN + 255) / 256, 256, 0, stream>>>(cnt, pool_sum, pool_cnt, N, B);
  k_wprep<<<9, 256, 0, stream>>>(Wm, att_s, att_d, Wh);
  k_xw<<<(N + 63) / 64, 256, 0, stream>>>(x, Wh, (_Float16*)xh, a_src, a_dst, N);
  k_count<<<(E + 255) / 256, 256, 0, stream>>>(ei, cnt, E);
  k_scanA<<<NB, 256, 0, stream>>>(cnt, offs, part, N);
  k_scanB<<<1, 1024, 0, stream>>>(part, NB);
  k_scanC<<<(N + 256) / 256, 256, 0, stream>>>(offs, part, N, NB);
  k_selfloop<<<(N + 255) / 256, 256, 0, stream>>>(offs, cursor, csr_src, N);
  k_fill<<<(E + 255) / 256, 256, 0, stream>>>(ei, cursor, csr_src, E);
  k_agg<<<(N + 3) / 4, 256, 0, stream>>>(csr_src, offs, a_src, a_dst, xh, bias, xout, N);
  k_pool<<<dim3(B, 4), 256, 0, stream>>>(xout, batch, pool_sum, pool_cnt, N);
  k_final<<<B, 128, 0, stream>>>(pool_sum, pool_cnt, lin_w, lin_b, out, B);
}

// Round 8
// 255.734 us; speedup vs baseline: 3.7952x; 1.3917x over previous
//
#include <hip/hip_runtime.h>
#include <hip/hip_fp16.h>

#define HC 128
#define FIN 128
#define NHEAD 4
#define NS_ATT 0.2f
#define NS_ACT 0.01f
#define NBLK_P 256      // partition blocks (must match k_hist/k_part chunking)
#define BCAP 14336      // LDS csr-segment capacity (ints) in k_build

typedef _Float16 half8 __attribute__((ext_vector_type(8)));
typedef float f32x4 __attribute__((ext_vector_type(4)));

__device__ __forceinline__ float lrelu(float v, float s) { return v >= 0.f ? v : s * v; }

__device__ __forceinline__ int lowerb(const int* __restrict__ a, int n, int v) {
  int lo = 0, hi = n;
  while (lo < hi) {
    int m = (lo + hi) >> 1;
    if (a[m] < v) lo = m + 1; else hi = m;
  }
  return lo;
}

// init: count=1 (self-loop), zero pooling buffers
__global__ void k_init(int* __restrict__ cnt, float* __restrict__ pool_sum,
                       int* __restrict__ pool_cnt, int N, int B) {
  int i = blockIdx.x * 256 + threadIdx.x;
  if (i < N) cnt[i] = 1;
  if (i < B * HC) pool_sum[i] = 0.f;
  if (i < B) pool_cnt[i] = 0;
}

// Pre-swizzle W into fp16 MFMA B-fragments + append W@att_src / W@att_dst columns.
__global__ void k_wprep(const float* __restrict__ W, const float* __restrict__ att_s,
                        const float* __restrict__ att_d, _Float16* __restrict__ Wh) {
  const int nt = blockIdx.x, t = threadIdx.x;
  const int kt = t >> 6, l = t & 63;
  const int c = nt * 16 + (l & 15);
  const int kbase = kt * 32 + (l >> 4) * 8;
  half8 v8;
#pragma unroll
  for (int j = 0; j < 8; ++j) {
    const int k = kbase + j;
    float v = 0.f;
    if (c < 128) {
      v = W[k * HC + c];
    } else if (c < 132) {
      const int h = c - 128;
      for (int cc = 0; cc < 32; ++cc) v += W[k * HC + h * 32 + cc] * att_s[h * 32 + cc];
    } else if (c < 136) {
      const int h = c - 132;
      for (int cc = 0; cc < 32; ++cc) v += W[k * HC + h * 32 + cc] * att_d[h * 32 + cc];
    }
    v8[j] = (_Float16)v;
  }
  ((half8*)Wh)[(nt * 4 + kt) * 64 + l] = v8;
}

// MFMA GEMM: xh = x@W (fp16 out) + a_src/a_dst from the appended tile.
__global__ __launch_bounds__(256) void k_xw(
    const float* __restrict__ x, const _Float16* __restrict__ Wh,
    _Float16* __restrict__ xh, float* __restrict__ a_src, float* __restrict__ a_dst,
    int N) {
  const int wv = threadIdx.x >> 6, l = threadIdx.x & 63;
  const int r0 = blockIdx.x * 64 + wv * 16;
  if (r0 >= N) return;
  const int row_a = r0 + (l & 15);
  const long arow = (long)min(row_a, N - 1) * FIN;
  const int kg = (l >> 4) * 8;
  half8 afr[4];
#pragma unroll
  for (int kt = 0; kt < 4; ++kt) {
    const float4 p0 = *(const float4*)(x + arow + kt * 32 + kg);
    const float4 p1 = *(const float4*)(x + arow + kt * 32 + kg + 4);
    afr[kt][0] = (_Float16)p0.x; afr[kt][1] = (_Float16)p0.y;
    afr[kt][2] = (_Float16)p0.z; afr[kt][3] = (_Float16)p0.w;
    afr[kt][4] = (_Float16)p1.x; afr[kt][5] = (_Float16)p1.y;
    afr[kt][6] = (_Float16)p1.z; afr[kt][7] = (_Float16)p1.w;
  }
  const half8* __restrict__ Wh8 = (const half8*)Wh;
  const int rbase = r0 + (l >> 4) * 4;
  const int cc = l & 15;
#pragma unroll
  for (int nt = 0; nt < 9; ++nt) {
    half8 b0 = Wh8[(nt * 4 + 0) * 64 + l];
    half8 b1 = Wh8[(nt * 4 + 1) * 64 + l];
    half8 b2 = Wh8[(nt * 4 + 2) * 64 + l];
    half8 b3 = Wh8[(nt * 4 + 3) * 64 + l];
    f32x4 acc = {0.f, 0.f, 0.f, 0.f};
    acc = __builtin_amdgcn_mfma_f32_16x16x32_f16(afr[0], b0, acc, 0, 0, 0);
    acc = __builtin_amdgcn_mfma_f32_16x16x32_f16(afr[1], b1, acc, 0, 0, 0);
    acc = __builtin_amdgcn_mfma_f32_16x16x32_f16(afr[2], b2, acc, 0, 0, 0);
    acc = __builtin_amdgcn_mfma_f32_16x16x32_f16(afr[3], b3, acc, 0, 0, 0);
    if (nt < 8) {
      const int col = nt * 16 + cc;
#pragma unroll
      for (int r = 0; r < 4; ++r) {
        const int row = rbase + r;
        if (row < N) xh[(long)row * HC + col] = (_Float16)acc[r];
      }
    } else if (cc < 8) {
      float* __restrict__ dst = (cc < 4) ? a_src : a_dst;
      const int h = cc & 3;
#pragma unroll
      for (int r = 0; r < 4; ++r) {
        const int row = rbase + r;
        if (row < N) dst[row * NHEAD + h] = acc[r];
      }
    }
  }
}

// fused: node-count atomics (old k_count) + per-block bucket histogram (bucket = d>>9)
__global__ __launch_bounds__(256) void k_hist(const int* __restrict__ ei, int* __restrict__ cnt,
                                              int* __restrict__ hist, int E, int NBUCK, int CH) {
  __shared__ int lc[512];
  for (int i = threadIdx.x; i < NBUCK; i += 256) lc[i] = 0;
  __syncthreads();
  const int e0 = blockIdx.x * CH, e1 = min(E, e0 + CH);
  for (int e = e0 + threadIdx.x; e < e1; e += 256) {
    const int d = ei[E + e];
    atomicAdd(&cnt[d], 1);
    atomicAdd(&lc[d >> 9], 1);
  }
  __syncthreads();
  for (int i = threadIdx.x; i < NBUCK; i += 256) hist[i * gridDim.x + blockIdx.x] = lc[i];
}

__global__ void k_scanA(const int* __restrict__ cnt, int* __restrict__ offs,
                        int* __restrict__ part, int N) {
  __shared__ int s[256];
  int t = threadIdx.x, i = blockIdx.x * 256 + t;
  int v = (i < N) ? cnt[i] : 0;
  s[t] = v;
#pragma unroll
  for (int off = 1; off < 256; off <<= 1) {
    __syncthreads();
    int u = (t >= off) ? s[t - off] : 0;
    __syncthreads();
    s[t] += u;
  }
  if (i < N) offs[i] = s[t] - v;
  if (t == 255) part[blockIdx.x] = s[255];
}

__global__ void k_scanB(int* __restrict__ part, int NB) {
  __shared__ int s[1024];
  int t = threadIdx.x;
  int v = (t < NB) ? part[t] : 0;
  s[t] = v;
#pragma unroll
  for (int off = 1; off < 1024; off <<= 1) {
    __syncthreads();
    int u = (t >= off) ? s[t - off] : 0;
    __syncthreads();
    s[t] += u;
  }
  if (t < NB) part[t] = s[t] - v;
  if (t == 1023) part[NB] = s[1023];
}

__global__ void k_scanC(int* __restrict__ offs, const int* __restrict__ part, int N, int NB) {
  int i = blockIdx.x * 256 + threadIdx.x;
  if (i < N) offs[i] += part[i >> 8];
  else if (i == N) offs[N] = part[NB];
}

// partition edges into dst-buckets; per-(block,bucket) runs are exact (scanned hist),
// so every csr line is written by one block only (XCD-local).
__global__ __launch_bounds__(256) void k_part(const int* __restrict__ ei,
                                              const int* __restrict__ histoffs,
                                              unsigned* __restrict__ ebuf,
                                              int E, int NBUCK, int CH) {
  __shared__ int lcur[512];
  for (int i = threadIdx.x; i < NBUCK; i += 256)
    lcur[i] = histoffs[i * gridDim.x + blockIdx.x];
  __syncthreads();
  const int e0 = blockIdx.x * CH, e1 = min(E, e0 + CH);
  for (int e = e0 + threadIdx.x; e < e1; e += 256) {
    const int s = ei[e], d = ei[E + e];
    const int pos = atomicAdd(&lcur[d >> 9], 1);
    ebuf[pos] = ((unsigned)(d & 511) << 18) | (unsigned)s;  // N <= 262144
  }
}

// global cursor init + self-loop placement (also the fallback path's cursors)
__global__ void k_selfloop(const int* __restrict__ offs, int* __restrict__ cursor,
                           int* __restrict__ csr_src, int N) {
  int i = blockIdx.x * 256 + threadIdx.x;
  if (i < N) {
    int o = offs[i];
    cursor[i] = o + 1;
    csr_src[o] = i;
  }
}

// one block per bucket: LDS scatter by node, coalesced segment write.
__global__ __launch_bounds__(256) void k_build(
    const int* __restrict__ offs, const int* __restrict__ histoffs,
    const unsigned* __restrict__ ebuf, int* __restrict__ csr_src,
    int* __restrict__ cursor, int N, int NBUCK) {
  const int b = blockIdx.x;
  const int n0 = b << 9, n1 = min(N, n0 + 512), nn = n1 - n0;
  const int seg0 = offs[n0], seg1 = offs[n1];
  const int L = seg1 - seg0;
  const int eb0 = histoffs[b * NBLK_P];
  const int eb1 = histoffs[(b + 1) * NBLK_P];
  __shared__ int cur[512];
  __shared__ int lcsr[BCAP];
  if (L <= BCAP) {
    for (int i = threadIdx.x; i < nn; i += 256) {
      const int o = offs[n0 + i] - seg0;
      lcsr[o] = n0 + i;          // self-loop at slot 0 of the node's segment
      cur[i] = o + 1;
    }
    __syncthreads();
    for (int e = eb0 + threadIdx.x; e < eb1; e += 256) {
      const unsigned pk = ebuf[e];
      const int dl = pk >> 18, s = (int)(pk & 0x3FFFFu);
      const int pos = atomicAdd(&cur[dl], 1);
      lcsr[pos] = s;
    }
    __syncthreads();
    for (int i = threadIdx.x; i < L; i += 256) csr_src[seg0 + i] = lcsr[i];
  } else {
    // fallback (data-independent correctness): global cursor scatter;
    // self-loops already placed by k_selfloop.
    for (int e = eb0 + threadIdx.x; e < eb1; e += 256) {
      const unsigned pk = ebuf[e];
      const int dl = pk >> 18, s = (int)(pk & 0x3FFFFu);
      const int pos = atomicAdd(&cursor[n0 + dl], 1);
      csr_src[pos] = s;
    }
  }
}

// one wave per dst node. fp16 xh gather; no atomics, plain store to xout.
__global__ __launch_bounds__(256) void k_agg(
    const int* __restrict__ csr_src, const int* __restrict__ offs,
    const float* __restrict__ a_src, const float* __restrict__ a_dst,
    const __half* __restrict__ xh, const float* __restrict__ bias,
    __half* __restrict__ xout, int N) {
  const int wid = (blockIdx.x * 256 + threadIdx.x) >> 6;
  const int lane = threadIdx.x & 63;
  if (wid >= N) return;
  const int n = wid;
  const int o0 = offs[n], deg = offs[n + 1] - o0;
  const float4 dv = ((const float4*)a_dst)[n];
  const int l16 = lane & 15, g = lane >> 4, h = l16 >> 2;
  const uint4* __restrict__ xh16 = (const uint4*)xh;

  float4 sm = make_float4(0.f, 0.f, 0.f, 0.f);
  float acc[8] = {0.f, 0.f, 0.f, 0.f, 0.f, 0.f, 0.f, 0.f};

  for (int c0 = 0; c0 < deg; c0 += 64) {
    const int cl = min(64, deg - c0);
    int sj = 0;
    float4 w4 = make_float4(0.f, 0.f, 0.f, 0.f);
    if (lane < cl) {
      sj = csr_src[o0 + c0 + lane];
      float4 av = ((const float4*)a_src)[sj];
      w4.x = __expf(lrelu(av.x + dv.x, NS_ATT));
      w4.y = __expf(lrelu(av.y + dv.y, NS_ATT));
      w4.z = __expf(lrelu(av.z + dv.z, NS_ATT));
      w4.w = __expf(lrelu(av.w + dv.w, NS_ATT));
      sm.x += w4.x; sm.y += w4.y; sm.z += w4.z; sm.w += w4.w;
    }
    for (int j = 0; j < cl; j += 16) {
      int s[4];
      float wsel[4];
      uint4 u[4];
#pragma unroll
      for (int q = 0; q < 4; ++q) {
        const int ee = j + q * 4 + g;
        const bool valid = ee < cl;
        const int es = ee & 63;
        const int ss = __shfl(sj, es);
        const float wx = __shfl(w4.x, es), wy = __shfl(w4.y, es);
        const float wz = __shfl(w4.z, es), ww = __shfl(w4.w, es);
        const float wv = (h == 0) ? wx : (h == 1) ? wy : (h == 2) ? wz : ww;
        wsel[q] = valid ? wv : 0.f;
        s[q] = valid ? ss : 0;
      }
#pragma unroll
      for (int q = 0; q < 4; ++q) {
        u[q] = xh16[(long)s[q] * 16 + l16];
      }
#pragma unroll
      for (int q = 0; q < 4; ++q) {
        const __half2* hp = (const __half2*)&u[q];
        const float2 f0 = __half22float2(hp[0]);
        const float2 f1 = __half22float2(hp[1]);
        const float2 f2 = __half22float2(hp[2]);
        const float2 f3 = __half22float2(hp[3]);
        acc[0] = fmaf(wsel[q], f0.x, acc[0]); acc[1] = fmaf(wsel[q], f0.y, acc[1]);
        acc[2] = fmaf(wsel[q], f1.x, acc[2]); acc[3] = fmaf(wsel[q], f1.y, acc[3]);
        acc[4] = fmaf(wsel[q], f2.x, acc[4]); acc[5] = fmaf(wsel[q], f2.y, acc[5]);
        acc[6] = fmaf(wsel[q], f3.x, acc[6]); acc[7] = fmaf(wsel[q], f3.y, acc[7]);
      }
    }
  }

#pragma unroll
  for (int m = 32; m >= 1; m >>= 1) {
    sm.x += __shfl_xor(sm.x, m);
    sm.y += __shfl_xor(sm.y, m);
    sm.z += __shfl_xor(sm.z, m);
    sm.w += __shfl_xor(sm.w, m);
  }
#pragma unroll
  for (int m = 32; m >= 16; m >>= 1) {
#pragma unroll
    for (int i = 0; i < 8; ++i) acc[i] += __shfl_xor(acc[i], m);
  }

  const float sh = (h == 0) ? sm.x : (h == 1) ? sm.y : (h == 2) ? sm.z : sm.w;
  const float inv = 1.f / (sh + 1e-16f);
  const int ch = l16 * 8 + g * 2;
  float r0 = lrelu(acc[2 * g] * inv + bias[ch], NS_ACT);
  float r1 = lrelu(acc[2 * g + 1] * inv + bias[ch + 1], NS_ACT);
  ((__half2*)(xout + (long)n * HC))[ch >> 1] = __floats2half2_rn(r0, r1);
}

// segmented mean-pool over sorted batch
__global__ __launch_bounds__(256) void k_pool(
    const __half* __restrict__ xout, const int* __restrict__ batch,
    float* __restrict__ pool_sum, int* __restrict__ pool_cnt, int N) {
  const int b = blockIdx.x, q = blockIdx.y, t = threadIdx.x;
  const int lo = lowerb(batch, N, b);
  const int hi = lowerb(batch, N, b + 1);
  const int cnt = hi - lo;
  if (q == 0 && t == 0) pool_cnt[b] = cnt;
  const int qlen = (cnt + 3) >> 2;
  const int qlo = lo + q * qlen;
  const int qhi = min(qlo + qlen, hi);

  const int c2 = t & 63;
  const int rs = t >> 6;
  const __half2* __restrict__ xo2 = (const __half2*)xout;
  float ax = 0.f, ay = 0.f, bx2 = 0.f, by2 = 0.f;
  int r = qlo + rs;
  for (; r + 4 < qhi; r += 8) {
    float2 f0 = __half22float2(xo2[(long)r * 64 + c2]);
    float2 f1 = __half22float2(xo2[(long)(r + 4) * 64 + c2]);
    ax += f0.x; ay += f0.y; bx2 += f1.x; by2 += f1.y;
  }
  for (; r < qhi; r += 4) {
    float2 f0 = __half22float2(xo2[(long)r * 64 + c2]);
    ax += f0.x; ay += f0.y;
  }
  __shared__ float2 sp[256];
  sp[t] = make_float2(ax + bx2, ay + by2);
  __syncthreads();
  if (t < 64) {
    float2 s0 = sp[t], s1 = sp[t + 64], s2 = sp[t + 128], s3 = sp[t + 192];
    atomicAdd(&pool_sum[b * HC + 2 * t], (s0.x + s1.x) + (s2.x + s3.x));
    atomicAdd(&pool_sum[b * HC + 2 * t + 1], (s0.y + s1.y) + (s2.y + s3.y));
  }
}

__global__ void k_final(const float* __restrict__ pool_sum, const int* __restrict__ pool_cnt,
                        const float* __restrict__ lin_w, const float* __restrict__ lin_b,
                        float* __restrict__ out, int B) {
  int b = blockIdx.x;
  __shared__ float pl[HC];
  int t = threadIdx.x;
  float c = fmaxf((float)pool_cnt[b], 1.0f);
  pl[t] = pool_sum[b * HC + t] / c;
  __syncthreads();
  if (t < 10) {
    float a = lin_b[t];
    for (int k = 0; k < HC; ++k) a = fmaf(pl[k], lin_w[t * HC + k], a);
    out[b * 10 + t] = a;
  }
}

extern "C" void kernel_launch(void* const* d_in, const int* in_sizes, int n_in,
                              void* d_out, int out_size, void* d_ws, size_t ws_size,
                              hipStream_t stream) {
  const float* x = (const float*)d_in[0];
  const int* ei = (const int*)d_in[1];
  const int* batch = (const int*)d_in[2];
  const float* Wm = (const float*)d_in[4];
  const float* att_s = (const float*)d_in[5];
  const float* att_d = (const float*)d_in[6];
  const float* bias = (const float*)d_in[7];
  const float* lin_w = (const float*)d_in[8];
  const float* lin_b = (const float*)d_in[9];
  float* out = (float*)d_out;

  const int N = in_sizes[2];
  const int E = in_sizes[1] / 2;
  const int B = out_size / 10;
  const int NB = (N + 255) / 256;          // node-scan blocks (<=1024 -> N <= 262144)
  const int NBUCK = (N + 511) >> 9;        // dst buckets (<=512)
  const int M = NBUCK * NBLK_P;            // hist entries
  const int NB2 = (M + 255) / 256;         // hist-scan blocks (<=1024)
  const int CH = (E + NBLK_P - 1) / NBLK_P;

  char* p = (char*)d_ws;
  auto carve = [&](size_t bytes) {
    void* r = (void*)p;
    p += (bytes + 255) & ~(size_t)255;
    return r;
  };
  __half* xh = (__half*)carve((size_t)N * HC * 2);
  __half* xout = (__half*)carve((size_t)N * HC * 2);
  float* a_src = (float*)carve((size_t)N * NHEAD * 4);
  float* a_dst = (float*)carve((size_t)N * NHEAD * 4);
  int* cnt = (int*)carve((size_t)N * 4);
  int* offs = (int*)carve((size_t)(N + 1) * 4);
  int* cursor = (int*)carve((size_t)N * 4);
  int* part = (int*)carve((size_t)(NB + 2) * 4);
  int* csr_src = (int*)carve((size_t)(N + (size_t)E) * 4);
  float* pool_sum = (float*)carve((size_t)B * HC * 4);
  int* pool_cnt = (int*)carve((size_t)B * 4);
  _Float16* Wh = (_Float16*)carve((size_t)9 * 4 * 64 * 8 * 2);

  // alias partition scratch into xout (k_build completes before k_agg writes xout)
  char* q = (char*)xout;
  auto carve2 = [&](size_t bytes) {
    void* r = (void*)q;
    q += (bytes + 255) & ~(size_t)255;
    return r;
  };
  unsigned* ebuf = (unsigned*)carve2((size_t)E * 4);
  int* hist = (int*)carve2((size_t)M * 4);
  int* histoffs = (int*)carve2((size_t)(M + 1) * 4);
  int* part2 = (int*)carve2((size_t)(NB2 + 2) * 4);

  const int initN = (N > B * HC) ? N : B * HC;
  k_init<<<(initN + 255) / 256, 256, 0, stream>>>(cnt, pool_sum, pool_cnt, N, B);
  k_wprep<<<9, 256, 0, stream>>>(Wm, att_s, att_d, Wh);
  k_xw<<<(N + 63) / 64, 256, 0, stream>>>(x, Wh, (_Float16*)xh, a_src, a_dst, N);
  k_hist<<<NBLK_P, 256, 0, stream>>>(ei, cnt, hist, E, NBUCK, CH);
  // node scan: cnt -> offs
  k_scanA<<<NB, 256, 0, stream>>>(cnt, offs, part, N);
  k_scanB<<<1, 1024, 0, stream>>>(part, NB);
  k_scanC<<<(N + 256) / 256, 256, 0, stream>>>(offs, part, N, NB);
  // hist scan: hist -> histoffs
  k_scanA<<<NB2, 256, 0, stream>>>(hist, histoffs, part2, M);
  k_scanB<<<1, 1024, 0, stream>>>(part2, NB2);
  k_scanC<<<(M + 256) / 256, 256, 0, stream>>>(histoffs, part2, M, NB2);
  k_part<<<NBLK_P, 256, 0, stream>>>(ei, histoffs, ebuf, E, NBUCK, CH);
  k_selfloop<<<(N + 255) / 256, 256, 0, stream>>>(offs, cursor, csr_src, N);
  k_build<<<NBUCK, 256, 0, stream>>>(offs, histoffs, ebuf, csr_src, cursor, N, NBUCK);
  k_agg<<<(N + 3) / 4, 256, 0, stream>>>(csr_src, offs, a_src, a_dst, xh, bias, xout, N);
  k_pool<<<dim3(B, 4), 256, 0, stream>>>(xout, batch, pool_sum, pool_cnt, N);
  k_final<<<B, 128, 0, stream>>>(pool_sum, pool_cnt, lin_w, lin_b, out, B);
}

// Round 9
// 190.222 us; speedup vs baseline: 5.1023x; 1.3444x over previous
//
#include <hip/hip_runtime.h>
#include <hip/hip_fp16.h>

#define HC 128
#define FIN 128
#define NHEAD 4
#define NS_ATT 0.2f
#define NS_ACT 0.01f
#define NBLK_P 256      // partition blocks (k_hist/k_part chunking)
#define BCAP 14336      // LDS csr-segment capacity (ints) in k_build

typedef _Float16 half8 __attribute__((ext_vector_type(8)));
typedef float f32x4 __attribute__((ext_vector_type(4)));

__device__ __forceinline__ float lrelu(float v, float s) { return v >= 0.f ? v : s * v; }

__device__ __forceinline__ int lowerb(const int* __restrict__ a, int n, int v) {
  int lo = 0, hi = n;
  while (lo < hi) {
    int m = (lo + hi) >> 1;
    if (a[m] < v) lo = m + 1; else hi = m;
  }
  return lo;
}

// zero pooling buffers only (node counts now derived in k_build)
__global__ void k_init(float* __restrict__ pool_sum, int* __restrict__ pool_cnt, int B) {
  int i = blockIdx.x * 256 + threadIdx.x;
  if (i < B * HC) pool_sum[i] = 0.f;
  if (i < B) pool_cnt[i] = 0;
}

// Pre-swizzle W into fp16 MFMA B-fragments + append W@att_src / W@att_dst columns.
__global__ void k_wprep(const float* __restrict__ W, const float* __restrict__ att_s,
                        const float* __restrict__ att_d, _Float16* __restrict__ Wh) {
  const int nt = blockIdx.x, t = threadIdx.x;
  const int kt = t >> 6, l = t & 63;
  const int c = nt * 16 + (l & 15);
  const int kbase = kt * 32 + (l >> 4) * 8;
  half8 v8;
#pragma unroll
  for (int j = 0; j < 8; ++j) {
    const int k = kbase + j;
    float v = 0.f;
    if (c < 128) {
      v = W[k * HC + c];
    } else if (c < 132) {
      const int h = c - 128;
      for (int cc = 0; cc < 32; ++cc) v += W[k * HC + h * 32 + cc] * att_s[h * 32 + cc];
    } else if (c < 136) {
      const int h = c - 132;
      for (int cc = 0; cc < 32; ++cc) v += W[k * HC + h * 32 + cc] * att_d[h * 32 + cc];
    }
    v8[j] = (_Float16)v;
  }
  ((half8*)Wh)[(nt * 4 + kt) * 64 + l] = v8;
}

// MFMA GEMM: xh = x@W (fp16 out) + a_src/a_dst from the appended tile.
__global__ __launch_bounds__(256) void k_xw(
    const float* __restrict__ x, const _Float16* __restrict__ Wh,
    _Float16* __restrict__ xh, float* __restrict__ a_src, float* __restrict__ a_dst,
    int N) {
  const int wv = threadIdx.x >> 6, l = threadIdx.x & 63;
  const int r0 = blockIdx.x * 64 + wv * 16;
  if (r0 >= N) return;
  const int row_a = r0 + (l & 15);
  const long arow = (long)min(row_a, N - 1) * FIN;
  const int kg = (l >> 4) * 8;
  half8 afr[4];
#pragma unroll
  for (int kt = 0; kt < 4; ++kt) {
    const float4 p0 = *(const float4*)(x + arow + kt * 32 + kg);
    const float4 p1 = *(const float4*)(x + arow + kt * 32 + kg + 4);
    afr[kt][0] = (_Float16)p0.x; afr[kt][1] = (_Float16)p0.y;
    afr[kt][2] = (_Float16)p0.z; afr[kt][3] = (_Float16)p0.w;
    afr[kt][4] = (_Float16)p1.x; afr[kt][5] = (_Float16)p1.y;
    afr[kt][6] = (_Float16)p1.z; afr[kt][7] = (_Float16)p1.w;
  }
  const half8* __restrict__ Wh8 = (const half8*)Wh;
  const int rbase = r0 + (l >> 4) * 4;
  const int cc = l & 15;
#pragma unroll
  for (int nt = 0; nt < 9; ++nt) {
    half8 b0 = Wh8[(nt * 4 + 0) * 64 + l];
    half8 b1 = Wh8[(nt * 4 + 1) * 64 + l];
    half8 b2 = Wh8[(nt * 4 + 2) * 64 + l];
    half8 b3 = Wh8[(nt * 4 + 3) * 64 + l];
    f32x4 acc = {0.f, 0.f, 0.f, 0.f};
    acc = __builtin_amdgcn_mfma_f32_16x16x32_f16(afr[0], b0, acc, 0, 0, 0);
    acc = __builtin_amdgcn_mfma_f32_16x16x32_f16(afr[1], b1, acc, 0, 0, 0);
    acc = __builtin_amdgcn_mfma_f32_16x16x32_f16(afr[2], b2, acc, 0, 0, 0);
    acc = __builtin_amdgcn_mfma_f32_16x16x32_f16(afr[3], b3, acc, 0, 0, 0);
    if (nt < 8) {
      const int col = nt * 16 + cc;
#pragma unroll
      for (int r = 0; r < 4; ++r) {
        const int row = rbase + r;
        if (row < N) xh[(long)row * HC + col] = (_Float16)acc[r];
      }
    } else if (cc < 8) {
      float* __restrict__ dst = (cc < 4) ? a_src : a_dst;
      const int h = cc & 3;
#pragma unroll
      for (int r = 0; r < 4; ++r) {
        const int row = rbase + r;
        if (row < N) dst[row * NHEAD + h] = acc[r];
      }
    }
  }
}

// per-block bucket histogram only (bucket = d>>9); no global node atomics
__global__ __launch_bounds__(256) void k_hist(const int* __restrict__ ei,
                                              int* __restrict__ hist, int E, int NBUCK, int CH) {
  __shared__ int lc[512];
  for (int i = threadIdx.x; i < NBUCK; i += 256) lc[i] = 0;
  __syncthreads();
  const int e0 = blockIdx.x * CH, e1 = min(E, e0 + CH);
  for (int e = e0 + threadIdx.x; e < e1; e += 256) {
    atomicAdd(&lc[ei[E + e] >> 9], 1);
  }
  __syncthreads();
  for (int i = threadIdx.x; i < NBUCK; i += 256) hist[i * gridDim.x + blockIdx.x] = lc[i];
}

__global__ void k_scanA(const int* __restrict__ cnt, int* __restrict__ offs,
                        int* __restrict__ part, int N) {
  __shared__ int s[256];
  int t = threadIdx.x, i = blockIdx.x * 256 + t;
  int v = (i < N) ? cnt[i] : 0;
  s[t] = v;
#pragma unroll
  for (int off = 1; off < 256; off <<= 1) {
    __syncthreads();
    int u = (t >= off) ? s[t - off] : 0;
    __syncthreads();
    s[t] += u;
  }
  if (i < N) offs[i] = s[t] - v;
  if (t == 255) part[blockIdx.x] = s[255];
}

__global__ void k_scanB(int* __restrict__ part, int NB) {
  __shared__ int s[1024];
  int t = threadIdx.x;
  int v = (t < NB) ? part[t] : 0;
  s[t] = v;
#pragma unroll
  for (int off = 1; off < 1024; off <<= 1) {
    __syncthreads();
    int u = (t >= off) ? s[t - off] : 0;
    __syncthreads();
    s[t] += u;
  }
  if (t < NB) part[t] = s[t] - v;
  if (t == 1023) part[NB] = s[1023];
}

__global__ void k_scanC(int* __restrict__ offs, const int* __restrict__ part, int N, int NB) {
  int i = blockIdx.x * 256 + threadIdx.x;
  if (i < N) offs[i] += part[i >> 8];
  else if (i == N) offs[N] = part[NB];
}

// partition edges into dst-buckets; per-(block,bucket) runs exact (scanned hist)
__global__ __launch_bounds__(256) void k_part(const int* __restrict__ ei,
                                              const int* __restrict__ histoffs,
                                              unsigned* __restrict__ ebuf,
                                              int E, int NBUCK, int CH) {
  __shared__ int lcur[512];
  for (int i = threadIdx.x; i < NBUCK; i += 256)
    lcur[i] = histoffs[i * gridDim.x + blockIdx.x];
  __syncthreads();
  const int e0 = blockIdx.x * CH, e1 = min(E, e0 + CH);
  for (int e = e0 + threadIdx.x; e < e1; e += 256) {
    const int s = ei[e], d = ei[E + e];
    const int pos = atomicAdd(&lcur[d >> 9], 1);
    ebuf[pos] = ((unsigned)(d & 511) << 18) | (unsigned)s;  // N <= 262144
  }
}

// one block per bucket: derive per-node counts from ebuf, LDS scan -> offs,
// place self-loops, LDS scatter, coalesced segment write. Fallback to
// bucket-local global scatter if segment exceeds LDS cap.
__global__ __launch_bounds__(256) void k_build(
    const int* __restrict__ histoffs, const unsigned* __restrict__ ebuf,
    int* __restrict__ csr_src, int* __restrict__ offs, int N) {
  const int b = blockIdx.x, t = threadIdx.x;
  const int n0 = b << 9, n1 = min(N, n0 + 512), nn = n1 - n0;
  const int eb0 = histoffs[b * NBLK_P];
  const int eb1 = histoffs[(b + 1) * NBLK_P];
  const int base = eb0 + n0;
  const int L = (eb1 - eb0) + nn;
  __shared__ int cnt2[512];
  __shared__ int scn[256];
  __shared__ int cur[512];
  __shared__ int lcsr[BCAP];
  cnt2[t] = 0; cnt2[t + 256] = 0;
  __syncthreads();
  for (int e = eb0 + t; e < eb1; e += 256) atomicAdd(&cnt2[ebuf[e] >> 18], 1);
  __syncthreads();
  // segment sizes (cnt+1 self-loop); scan 512 via 2 elems/thread
  const int i0 = 2 * t, i1 = 2 * t + 1;
  const int a0 = (i0 < nn) ? cnt2[i0] + 1 : 0;
  const int a1 = (i1 < nn) ? cnt2[i1] + 1 : 0;
  scn[t] = a0 + a1;
  for (int off = 1; off < 256; off <<= 1) {
    __syncthreads();
    int u = (t >= off) ? scn[t - off] : 0;
    __syncthreads();
    scn[t] += u;
  }
  __syncthreads();
  const int ex = scn[t] - (a0 + a1);
  const int o0 = ex, o1 = ex + a0;
  if (i0 < nn) offs[n0 + i0] = base + o0;
  if (i1 < nn) offs[n0 + i1] = base + o1;
  if (t == 255 && n1 == N) offs[N] = base + scn[255];
  if (L <= BCAP) {
    if (i0 < nn) { lcsr[o0] = n0 + i0; cur[i0] = o0 + 1; }
    if (i1 < nn) { lcsr[o1] = n0 + i1; cur[i1] = o1 + 1; }
    __syncthreads();
    for (int e = eb0 + t; e < eb1; e += 256) {
      const unsigned pk = ebuf[e];
      const int pos = atomicAdd(&cur[pk >> 18], 1);
      lcsr[pos] = (int)(pk & 0x3FFFFu);
    }
    __syncthreads();
    for (int i = t; i < L; i += 256) csr_src[base + i] = lcsr[i];
  } else {
    if (i0 < nn) { csr_src[base + o0] = n0 + i0; cur[i0] = base + o0 + 1; }
    if (i1 < nn) { csr_src[base + o1] = n0 + i1; cur[i1] = base + o1 + 1; }
    __syncthreads();
    for (int e = eb0 + t; e < eb1; e += 256) {
      const unsigned pk = ebuf[e];
      const int pos = atomicAdd(&cur[pk >> 18], 1);
      csr_src[pos] = (int)(pk & 0x3FFFFu);
    }
  }
}

// one wave per dst node. fp16 xh gather; LDS-staged per-edge weights/indices
// (pad-5 layout: conflict-free) instead of shfl broadcast. No atomics.
__global__ __launch_bounds__(256) void k_agg(
    const int* __restrict__ csr_src, const int* __restrict__ offs,
    const float* __restrict__ a_src, const float* __restrict__ a_dst,
    const __half* __restrict__ xh, const float* __restrict__ bias,
    __half* __restrict__ xout, int N) {
  __shared__ float wls[4][64 * 5];
  __shared__ int sls[4][64];
  const int wv = threadIdx.x >> 6;
  const int wid = (blockIdx.x * 256 + threadIdx.x) >> 6;
  const int lane = threadIdx.x & 63;
  if (wid >= N) return;
  float* __restrict__ wl = wls[wv];
  int* __restrict__ sl = sls[wv];
  const int n = wid;
  const int o0 = offs[n], deg = offs[n + 1] - o0;
  const float4 dv = ((const float4*)a_dst)[n];
  const int l16 = lane & 15, g = lane >> 4, h = l16 >> 2;
  const uint4* __restrict__ xh16 = (const uint4*)xh;

  float4 sm = make_float4(0.f, 0.f, 0.f, 0.f);
  float acc[8] = {0.f, 0.f, 0.f, 0.f, 0.f, 0.f, 0.f, 0.f};

  for (int c0 = 0; c0 < deg; c0 += 64) {
    const int cl = min(64, deg - c0);
    if (lane < cl) {
      const int sj = csr_src[o0 + c0 + lane];
      const float4 av = ((const float4*)a_src)[sj];
      const float w0 = __expf(lrelu(av.x + dv.x, NS_ATT));
      const float w1 = __expf(lrelu(av.y + dv.y, NS_ATT));
      const float w2 = __expf(lrelu(av.z + dv.z, NS_ATT));
      const float w3 = __expf(lrelu(av.w + dv.w, NS_ATT));
      sm.x += w0; sm.y += w1; sm.z += w2; sm.w += w3;
      sl[lane] = sj;
      wl[lane * 5 + 0] = w0; wl[lane * 5 + 1] = w1;
      wl[lane * 5 + 2] = w2; wl[lane * 5 + 3] = w3;
    }
    for (int j = 0; j < cl; j += 16) {
      int s[4];
      float wsel[4];
      uint4 u[4];
#pragma unroll
      for (int q = 0; q < 4; ++q) {
        const int ee = j + q * 4 + g;   // always < 64
        const bool valid = ee < cl;
        const float wv_ = wl[ee * 5 + h];
        const int ss = sl[ee];
        wsel[q] = valid ? wv_ : 0.f;
        s[q] = valid ? ss : 0;
      }
#pragma unroll
      for (int q = 0; q < 4; ++q) {
        u[q] = xh16[(long)s[q] * 16 + l16];
      }
#pragma unroll
      for (int q = 0; q < 4; ++q) {
        const __half2* hp = (const __half2*)&u[q];
        const float2 f0 = __half22float2(hp[0]);
        const float2 f1 = __half22float2(hp[1]);
        const float2 f2 = __half22float2(hp[2]);
        const float2 f3 = __half22float2(hp[3]);
        acc[0] = fmaf(wsel[q], f0.x, acc[0]); acc[1] = fmaf(wsel[q], f0.y, acc[1]);
        acc[2] = fmaf(wsel[q], f1.x, acc[2]); acc[3] = fmaf(wsel[q], f1.y, acc[3]);
        acc[4] = fmaf(wsel[q], f2.x, acc[4]); acc[5] = fmaf(wsel[q], f2.y, acc[5]);
        acc[6] = fmaf(wsel[q], f3.x, acc[6]); acc[7] = fmaf(wsel[q], f3.y, acc[7]);
      }
    }
  }

#pragma unroll
  for (int m = 32; m >= 1; m >>= 1) {
    sm.x += __shfl_xor(sm.x, m);
    sm.y += __shfl_xor(sm.y, m);
    sm.z += __shfl_xor(sm.z, m);
    sm.w += __shfl_xor(sm.w, m);
  }
#pragma unroll
  for (int m = 32; m >= 16; m >>= 1) {
#pragma unroll
    for (int i = 0; i < 8; ++i) acc[i] += __shfl_xor(acc[i], m);
  }

  const float sh = (h == 0) ? sm.x : (h == 1) ? sm.y : (h == 2) ? sm.z : sm.w;
  const float inv = 1.f / (sh + 1e-16f);
  const int ch = l16 * 8 + g * 2;
  float r0 = lrelu(acc[2 * g] * inv + bias[ch], NS_ACT);
  float r1 = lrelu(acc[2 * g + 1] * inv + bias[ch + 1], NS_ACT);
  ((__half2*)(xout + (long)n * HC))[ch >> 1] = __floats2half2_rn(r0, r1);
}

// segmented mean-pool over sorted batch
__global__ __launch_bounds__(256) void k_pool(
    const __half* __restrict__ xout, const int* __restrict__ batch,
    float* __restrict__ pool_sum, int* __restrict__ pool_cnt, int N) {
  const int b = blockIdx.x, q = blockIdx.y, t = threadIdx.x;
  const int lo = lowerb(batch, N, b);
  const int hi = lowerb(batch, N, b + 1);
  const int cnt = hi - lo;
  if (q == 0 && t == 0) pool_cnt[b] = cnt;
  const int qlen = (cnt + 3) >> 2;
  const int qlo = lo + q * qlen;
  const int qhi = min(qlo + qlen, hi);

  const int c2 = t & 63;
  const int rs = t >> 6;
  const __half2* __restrict__ xo2 = (const __half2*)xout;
  float ax = 0.f, ay = 0.f, bx2 = 0.f, by2 = 0.f;
  int r = qlo + rs;
  for (; r + 4 < qhi; r += 8) {
    float2 f0 = __half22float2(xo2[(long)r * 64 + c2]);
    float2 f1 = __half22float2(xo2[(long)(r + 4) * 64 + c2]);
    ax += f0.x; ay += f0.y; bx2 += f1.x; by2 += f1.y;
  }
  for (; r < qhi; r += 4) {
    float2 f0 = __half22float2(xo2[(long)r * 64 + c2]);
    ax += f0.x; ay += f0.y;
  }
  __shared__ float2 sp[256];
  sp[t] = make_float2(ax + bx2, ay + by2);
  __syncthreads();
  if (t < 64) {
    float2 s0 = sp[t], s1 = sp[t + 64], s2 = sp[t + 128], s3 = sp[t + 192];
    atomicAdd(&pool_sum[b * HC + 2 * t], (s0.x + s1.x) + (s2.x + s3.x));
    atomicAdd(&pool_sum[b * HC + 2 * t + 1], (s0.y + s1.y) + (s2.y + s3.y));
  }
}

__global__ void k_final(const float* __restrict__ pool_sum, const int* __restrict__ pool_cnt,
                        const float* __restrict__ lin_w, const float* __restrict__ lin_b,
                        float* __restrict__ out, int B) {
  int b = blockIdx.x;
  __shared__ float pl[HC];
  int t = threadIdx.x;
  float c = fmaxf((float)pool_cnt[b], 1.0f);
  pl[t] = pool_sum[b * HC + t] / c;
  __syncthreads();
  if (t < 10) {
    float a = lin_b[t];
    for (int k = 0; k < HC; ++k) a = fmaf(pl[k], lin_w[t * HC + k], a);
    out[b * 10 + t] = a;
  }
}

extern "C" void kernel_launch(void* const* d_in, const int* in_sizes, int n_in,
                              void* d_out, int out_size, void* d_ws, size_t ws_size,
                              hipStream_t stream) {
  const float* x = (const float*)d_in[0];
  const int* ei = (const int*)d_in[1];
  const int* batch = (const int*)d_in[2];
  const float* Wm = (const float*)d_in[4];
  const float* att_s = (const float*)d_in[5];
  const float* att_d = (const float*)d_in[6];
  const float* bias = (const float*)d_in[7];
  const float* lin_w = (const float*)d_in[8];
  const float* lin_b = (const float*)d_in[9];
  float* out = (float*)d_out;

  const int N = in_sizes[2];
  const int E = in_sizes[1] / 2;
  const int B = out_size / 10;
  const int NBUCK = (N + 511) >> 9;        // dst buckets (<=512)
  const int M = NBUCK * NBLK_P;            // hist entries
  const int NB2 = (M + 255) / 256;         // hist-scan blocks (<=1024)
  const int CH = (E + NBLK_P - 1) / NBLK_P;

  char* p = (char*)d_ws;
  auto carve = [&](size_t bytes) {
    void* r = (void*)p;
    p += (bytes + 255) & ~(size_t)255;
    return r;
  };
  __half* xh = (__half*)carve((size_t)N * HC * 2);
  __half* xout = (__half*)carve((size_t)N * HC * 2);
  float* a_src = (float*)carve((size_t)N * NHEAD * 4);
  float* a_dst = (float*)carve((size_t)N * NHEAD * 4);
  int* offs = (int*)carve((size_t)(N + 1) * 4);
  int* csr_src = (int*)carve((size_t)(N + (size_t)E) * 4);
  float* pool_sum = (float*)carve((size_t)B * HC * 4);
  int* pool_cnt = (int*)carve((size_t)B * 4);
  _Float16* Wh = (_Float16*)carve((size_t)9 * 4 * 64 * 8 * 2);

  // alias partition scratch into xout (consumed by k_build before k_agg writes xout)
  char* q = (char*)xout;
  auto carve2 = [&](size_t bytes) {
    void* r = (void*)q;
    q += (bytes + 255) & ~(size_t)255;
    return r;
  };
  unsigned* ebuf = (unsigned*)carve2((size_t)E * 4);
  int* hist = (int*)carve2((size_t)M * 4);
  int* histoffs = (int*)carve2((size_t)(M + 1) * 4);
  int* part2 = (int*)carve2((size_t)(NB2 + 2) * 4);

  k_init<<<(B * HC + 255) / 256, 256, 0, stream>>>(pool_sum, pool_cnt, B);
  k_wprep<<<9, 256, 0, stream>>>(Wm, att_s, att_d, Wh);
  k_xw<<<(N + 63) / 64, 256, 0, stream>>>(x, Wh, (_Float16*)xh, a_src, a_dst, N);
  k_hist<<<NBLK_P, 256, 0, stream>>>(ei, hist, E, NBUCK, CH);
  k_scanA<<<NB2, 256, 0, stream>>>(hist, histoffs, part2, M);
  k_scanB<<<1, 1024, 0, stream>>>(part2, NB2);
  k_scanC<<<(M + 256) / 256, 256, 0, stream>>>(histoffs, part2, M, NB2);
  k_part<<<NBLK_P, 256, 0, stream>>>(ei, histoffs, ebuf, E, NBUCK, CH);
  k_build<<<NBUCK, 256, 0, stream>>>(histoffs, ebuf, csr_src, offs, N);
  k_agg<<<(N + 3) / 4, 256, 0, stream>>>(csr_src, offs, a_src, a_dst, xh, bias, xout, N);
  k_pool<<<dim3(B, 4), 256, 0, stream>>>(xout, batch, pool_sum, pool_cnt, N);
  k_final<<<B, 128, 0, stream>>>(pool_sum, pool_cnt, lin_w, lin_b, out, B);
}

// Round 10
// 189.824 us; speedup vs baseline: 5.1130x; 1.0021x over previous
//
#include <hip/hip_runtime.h>
#include <hip/hip_fp16.h>

#define HC 128
#define FIN 128
#define NHEAD 4
#define NS_ATT 0.2f
#define NS_ACT 0.01f
#define NBLK_P 256      // partition blocks (k_hist/k_part chunking)
#define BCAP 14336      // LDS csr-segment capacity (ints) in k_build

typedef _Float16 half8 __attribute__((ext_vector_type(8)));
typedef float f32x4 __attribute__((ext_vector_type(4)));

__device__ __forceinline__ float lrelu(float v, float s) { return v >= 0.f ? v : s * v; }

__device__ __forceinline__ int lowerb(const int* __restrict__ a, int n, int v) {
  int lo = 0, hi = n;
  while (lo < hi) {
    int m = (lo + hi) >> 1;
    if (a[m] < v) lo = m + 1; else hi = m;
  }
  return lo;
}

// Pre-swizzle W into fp16 MFMA B-fragments + append W@att_src / W@att_dst columns.
__global__ void k_wprep(const float* __restrict__ W, const float* __restrict__ att_s,
                        const float* __restrict__ att_d, _Float16* __restrict__ Wh) {
  const int nt = blockIdx.x, t = threadIdx.x;
  const int kt = t >> 6, l = t & 63;
  const int c = nt * 16 + (l & 15);
  const int kbase = kt * 32 + (l >> 4) * 8;
  half8 v8;
#pragma unroll
  for (int j = 0; j < 8; ++j) {
    const int k = kbase + j;
    float v = 0.f;
    if (c < 128) {
      v = W[k * HC + c];
    } else if (c < 132) {
      const int h = c - 128;
      for (int cc = 0; cc < 32; ++cc) v += W[k * HC + h * 32 + cc] * att_s[h * 32 + cc];
    } else if (c < 136) {
      const int h = c - 132;
      for (int cc = 0; cc < 32; ++cc) v += W[k * HC + h * 32 + cc] * att_d[h * 32 + cc];
    }
    v8[j] = (_Float16)v;
  }
  ((half8*)Wh)[(nt * 4 + kt) * 64 + l] = v8;
}

// MFMA GEMM: xh = x@W (fp16 out) + a_src/a_dst from the appended tile.
__global__ __launch_bounds__(256) void k_xw(
    const float* __restrict__ x, const _Float16* __restrict__ Wh,
    _Float16* __restrict__ xh, float* __restrict__ a_src, float* __restrict__ a_dst,
    int N) {
  const int wv = threadIdx.x >> 6, l = threadIdx.x & 63;
  const int r0 = blockIdx.x * 64 + wv * 16;
  if (r0 >= N) return;
  const int row_a = r0 + (l & 15);
  const long arow = (long)min(row_a, N - 1) * FIN;
  const int kg = (l >> 4) * 8;
  half8 afr[4];
#pragma unroll
  for (int kt = 0; kt < 4; ++kt) {
    const float4 p0 = *(const float4*)(x + arow + kt * 32 + kg);
    const float4 p1 = *(const float4*)(x + arow + kt * 32 + kg + 4);
    afr[kt][0] = (_Float16)p0.x; afr[kt][1] = (_Float16)p0.y;
    afr[kt][2] = (_Float16)p0.z; afr[kt][3] = (_Float16)p0.w;
    afr[kt][4] = (_Float16)p1.x; afr[kt][5] = (_Float16)p1.y;
    afr[kt][6] = (_Float16)p1.z; afr[kt][7] = (_Float16)p1.w;
  }
  const half8* __restrict__ Wh8 = (const half8*)Wh;
  const int rbase = r0 + (l >> 4) * 4;
  const int cc = l & 15;
#pragma unroll
  for (int nt = 0; nt < 9; ++nt) {
    half8 b0 = Wh8[(nt * 4 + 0) * 64 + l];
    half8 b1 = Wh8[(nt * 4 + 1) * 64 + l];
    half8 b2 = Wh8[(nt * 4 + 2) * 64 + l];
    half8 b3 = Wh8[(nt * 4 + 3) * 64 + l];
    f32x4 acc = {0.f, 0.f, 0.f, 0.f};
    acc = __builtin_amdgcn_mfma_f32_16x16x32_f16(afr[0], b0, acc, 0, 0, 0);
    acc = __builtin_amdgcn_mfma_f32_16x16x32_f16(afr[1], b1, acc, 0, 0, 0);
    acc = __builtin_amdgcn_mfma_f32_16x16x32_f16(afr[2], b2, acc, 0, 0, 0);
    acc = __builtin_amdgcn_mfma_f32_16x16x32_f16(afr[3], b3, acc, 0, 0, 0);
    if (nt < 8) {
      const int col = nt * 16 + cc;
#pragma unroll
      for (int r = 0; r < 4; ++r) {
        const int row = rbase + r;
        if (row < N) xh[(long)row * HC + col] = (_Float16)acc[r];
      }
    } else if (cc < 8) {
      float* __restrict__ dst = (cc < 4) ? a_src : a_dst;
      const int h = cc & 3;
#pragma unroll
      for (int r = 0; r < 4; ++r) {
        const int row = rbase + r;
        if (row < N) dst[row * NHEAD + h] = acc[r];
      }
    }
  }
}

// per-block bucket histogram (bucket = d>>9)
__global__ __launch_bounds__(256) void k_hist(const int* __restrict__ ei,
                                              int* __restrict__ hist, int E, int NBUCK, int CH) {
  __shared__ int lc[512];
  for (int i = threadIdx.x; i < NBUCK; i += 256) lc[i] = 0;
  __syncthreads();
  const int e0 = blockIdx.x * CH, e1 = min(E, e0 + CH);
  for (int e = e0 + threadIdx.x; e < e1; e += 256) {
    atomicAdd(&lc[ei[E + e] >> 9], 1);
  }
  __syncthreads();
  for (int i = threadIdx.x; i < NBUCK; i += 256) hist[i * gridDim.x + blockIdx.x] = lc[i];
}

__global__ void k_scanA(const int* __restrict__ cnt, int* __restrict__ offs,
                        int* __restrict__ part, int N) {
  __shared__ int s[256];
  int t = threadIdx.x, i = blockIdx.x * 256 + t;
  int v = (i < N) ? cnt[i] : 0;
  s[t] = v;
#pragma unroll
  for (int off = 1; off < 256; off <<= 1) {
    __syncthreads();
    int u = (t >= off) ? s[t - off] : 0;
    __syncthreads();
    s[t] += u;
  }
  if (i < N) offs[i] = s[t] - v;
  if (t == 255) part[blockIdx.x] = s[255];
}

__global__ void k_scanB(int* __restrict__ part, int NB) {
  __shared__ int s[1024];
  int t = threadIdx.x;
  int v = (t < NB) ? part[t] : 0;
  s[t] = v;
#pragma unroll
  for (int off = 1; off < 1024; off <<= 1) {
    __syncthreads();
    int u = (t >= off) ? s[t - off] : 0;
    __syncthreads();
    s[t] += u;
  }
  if (t < NB) part[t] = s[t] - v;
  if (t == 1023) part[NB] = s[1023];
}

__global__ void k_scanC(int* __restrict__ offs, const int* __restrict__ part, int N, int NB) {
  int i = blockIdx.x * 256 + threadIdx.x;
  if (i < N) offs[i] += part[i >> 8];
  else if (i == N) offs[N] = part[NB];
}

// partition edges into dst-buckets; per-(block,bucket) runs exact (scanned hist)
__global__ __launch_bounds__(256) void k_part(const int* __restrict__ ei,
                                              const int* __restrict__ histoffs,
                                              unsigned* __restrict__ ebuf,
                                              int E, int NBUCK, int CH) {
  __shared__ int lcur[512];
  for (int i = threadIdx.x; i < NBUCK; i += 256)
    lcur[i] = histoffs[i * gridDim.x + blockIdx.x];
  __syncthreads();
  const int e0 = blockIdx.x * CH, e1 = min(E, e0 + CH);
  for (int e = e0 + threadIdx.x; e < e1; e += 256) {
    const int s = ei[e], d = ei[E + e];
    const int pos = atomicAdd(&lcur[d >> 9], 1);
    ebuf[pos] = ((unsigned)(d & 511) << 18) | (unsigned)s;  // N <= 262144
  }
}

// one block per bucket: per-node counts from ebuf, LDS scan -> offs, self-loops,
// LDS scatter, coalesced segment write; global fallback if segment > LDS cap.
__global__ __launch_bounds__(256) void k_build(
    const int* __restrict__ histoffs, const unsigned* __restrict__ ebuf,
    int* __restrict__ csr_src, int* __restrict__ offs, int N) {
  const int b = blockIdx.x, t = threadIdx.x;
  const int n0 = b << 9, n1 = min(N, n0 + 512), nn = n1 - n0;
  const int eb0 = histoffs[b * NBLK_P];
  const int eb1 = histoffs[(b + 1) * NBLK_P];
  const int base = eb0 + n0;
  const int L = (eb1 - eb0) + nn;
  __shared__ int cnt2[512];
  __shared__ int scn[256];
  __shared__ int cur[512];
  __shared__ int lcsr[BCAP];
  cnt2[t] = 0; cnt2[t + 256] = 0;
  __syncthreads();
  for (int e = eb0 + t; e < eb1; e += 256) atomicAdd(&cnt2[ebuf[e] >> 18], 1);
  __syncthreads();
  const int i0 = 2 * t, i1 = 2 * t + 1;
  const int a0 = (i0 < nn) ? cnt2[i0] + 1 : 0;
  const int a1 = (i1 < nn) ? cnt2[i1] + 1 : 0;
  scn[t] = a0 + a1;
  for (int off = 1; off < 256; off <<= 1) {
    __syncthreads();
    int u = (t >= off) ? scn[t - off] : 0;
    __syncthreads();
    scn[t] += u;
  }
  __syncthreads();
  const int ex = scn[t] - (a0 + a1);
  const int o0 = ex, o1 = ex + a0;
  if (i0 < nn) offs[n0 + i0] = base + o0;
  if (i1 < nn) offs[n0 + i1] = base + o1;
  if (t == 255 && n1 == N) offs[N] = base + scn[255];
  if (L <= BCAP) {
    if (i0 < nn) { lcsr[o0] = n0 + i0; cur[i0] = o0 + 1; }
    if (i1 < nn) { lcsr[o1] = n0 + i1; cur[i1] = o1 + 1; }
    __syncthreads();
    for (int e = eb0 + t; e < eb1; e += 256) {
      const unsigned pk = ebuf[e];
      const int pos = atomicAdd(&cur[pk >> 18], 1);
      lcsr[pos] = (int)(pk & 0x3FFFFu);
    }
    __syncthreads();
    for (int i = t; i < L; i += 256) csr_src[base + i] = lcsr[i];
  } else {
    if (i0 < nn) { csr_src[base + o0] = n0 + i0; cur[i0] = base + o0 + 1; }
    if (i1 < nn) { csr_src[base + o1] = n0 + i1; cur[i1] = base + o1 + 1; }
    __syncthreads();
    for (int e = eb0 + t; e < eb1; e += 256) {
      const unsigned pk = ebuf[e];
      const int pos = atomicAdd(&cur[pk >> 18], 1);
      csr_src[pos] = (int)(pk & 0x3FFFFu);
    }
  }
}

// one wave per dst node. fp16 xh gather; zero-padded LDS staging -> guard-free
// inner loops; 16-edge bulk steps + 4-edge tail steps (less padded work).
__global__ __launch_bounds__(256) void k_agg(
    const int* __restrict__ csr_src, const int* __restrict__ offs,
    const float* __restrict__ a_src, const float* __restrict__ a_dst,
    const __half* __restrict__ xh, const float* __restrict__ bias,
    __half* __restrict__ xout, int N) {
  __shared__ float wls[4][64 * 5];
  __shared__ int sls[4][64];
  const int wv = threadIdx.x >> 6;
  const int wid = (blockIdx.x * 256 + threadIdx.x) >> 6;
  const int lane = threadIdx.x & 63;
  if (wid >= N) return;
  float* __restrict__ wl = wls[wv];
  int* __restrict__ sl = sls[wv];
  const int n = wid;
  const int o0 = offs[n], deg = offs[n + 1] - o0;
  const float4 dv = ((const float4*)a_dst)[n];
  const int l16 = lane & 15, g = lane >> 4, h = l16 >> 2;
  const uint4* __restrict__ xh16 = (const uint4*)xh;

  float4 sm = make_float4(0.f, 0.f, 0.f, 0.f);
  float acc[8] = {0.f, 0.f, 0.f, 0.f, 0.f, 0.f, 0.f, 0.f};

  for (int c0 = 0; c0 < deg; c0 += 64) {
    const int cl = min(64, deg - c0);
    if (lane < cl) {
      const int sj = csr_src[o0 + c0 + lane];
      const float4 av = ((const float4*)a_src)[sj];
      const float w0 = __expf(lrelu(av.x + dv.x, NS_ATT));
      const float w1 = __expf(lrelu(av.y + dv.y, NS_ATT));
      const float w2 = __expf(lrelu(av.z + dv.z, NS_ATT));
      const float w3 = __expf(lrelu(av.w + dv.w, NS_ATT));
      sm.x += w0; sm.y += w1; sm.z += w2; sm.w += w3;
      sl[lane] = sj;
      wl[lane * 5 + 0] = w0; wl[lane * 5 + 1] = w1;
      wl[lane * 5 + 2] = w2; wl[lane * 5 + 3] = w3;
    } else {
      // zero-pad: inner loops run guard-free over padded slots
      sl[lane] = 0;
      wl[lane * 5 + 0] = 0.f; wl[lane * 5 + 1] = 0.f;
      wl[lane * 5 + 2] = 0.f; wl[lane * 5 + 3] = 0.f;
    }
    int j = 0;
    for (; j + 16 <= cl; j += 16) {            // bulk: 16 edges, 4 loads in flight
      int s[4];
      float wsel[4];
      uint4 u[4];
#pragma unroll
      for (int q = 0; q < 4; ++q) {
        const int ee = j + q * 4 + g;
        wsel[q] = wl[ee * 5 + h];
        s[q] = sl[ee];
      }
#pragma unroll
      for (int q = 0; q < 4; ++q) u[q] = xh16[(long)s[q] * 16 + l16];
#pragma unroll
      for (int q = 0; q < 4; ++q) {
        const __half2* hp = (const __half2*)&u[q];
        const float2 f0 = __half22float2(hp[0]);
        const float2 f1 = __half22float2(hp[1]);
        const float2 f2 = __half22float2(hp[2]);
        const float2 f3 = __half22float2(hp[3]);
        acc[0] = fmaf(wsel[q], f0.x, acc[0]); acc[1] = fmaf(wsel[q], f0.y, acc[1]);
        acc[2] = fmaf(wsel[q], f1.x, acc[2]); acc[3] = fmaf(wsel[q], f1.y, acc[3]);
        acc[4] = fmaf(wsel[q], f2.x, acc[4]); acc[5] = fmaf(wsel[q], f2.y, acc[5]);
        acc[6] = fmaf(wsel[q], f3.x, acc[6]); acc[7] = fmaf(wsel[q], f3.y, acc[7]);
      }
    }
    for (; j < cl; j += 4) {                   // tail: 4 edges (padded slots give 0)
      const int ee = j + g;
      const float w = wl[ee * 5 + h];
      const uint4 u = xh16[(long)sl[ee] * 16 + l16];
      const __half2* hp = (const __half2*)&u;
      const float2 f0 = __half22float2(hp[0]);
      const float2 f1 = __half22float2(hp[1]);
      const float2 f2 = __half22float2(hp[2]);
      const float2 f3 = __half22float2(hp[3]);
      acc[0] = fmaf(w, f0.x, acc[0]); acc[1] = fmaf(w, f0.y, acc[1]);
      acc[2] = fmaf(w, f1.x, acc[2]); acc[3] = fmaf(w, f1.y, acc[3]);
      acc[4] = fmaf(w, f2.x, acc[4]); acc[5] = fmaf(w, f2.y, acc[5]);
      acc[6] = fmaf(w, f3.x, acc[6]); acc[7] = fmaf(w, f3.y, acc[7]);
    }
  }

#pragma unroll
  for (int m = 32; m >= 1; m >>= 1) {
    sm.x += __shfl_xor(sm.x, m);
    sm.y += __shfl_xor(sm.y, m);
    sm.z += __shfl_xor(sm.z, m);
    sm.w += __shfl_xor(sm.w, m);
  }
#pragma unroll
  for (int m = 32; m >= 16; m >>= 1) {
#pragma unroll
    for (int i = 0; i < 8; ++i) acc[i] += __shfl_xor(acc[i], m);
  }

  const float sh = (h == 0) ? sm.x : (h == 1) ? sm.y : (h == 2) ? sm.z : sm.w;
  const float inv = 1.f / (sh + 1e-16f);
  const int ch = l16 * 8 + g * 2;
  float r0 = lrelu(acc[2 * g] * inv + bias[ch], NS_ACT);
  float r1 = lrelu(acc[2 * g + 1] * inv + bias[ch + 1], NS_ACT);
  ((__half2*)(xout + (long)n * HC))[ch >> 1] = __floats2half2_rn(r0, r1);
}

// segmented mean-pool partials: grid (B,4); plain stores, no atomics/init.
__global__ __launch_bounds__(256) void k_pool(
    const __half* __restrict__ xout, const int* __restrict__ batch,
    float* __restrict__ pool_part, int N) {
  const int b = blockIdx.x, q = blockIdx.y, t = threadIdx.x;
  const int lo = lowerb(batch, N, b);
  const int hi = lowerb(batch, N, b + 1);
  const int cnt = hi - lo;
  const int qlen = (cnt + 3) >> 2;
  const int qlo = lo + q * qlen;
  const int qhi = min(qlo + qlen, hi);

  const int c2 = t & 63;
  const int rs = t >> 6;
  const __half2* __restrict__ xo2 = (const __half2*)xout;
  float ax = 0.f, ay = 0.f, bx2 = 0.f, by2 = 0.f;
  int r = qlo + rs;
  for (; r + 4 < qhi; r += 8) {
    float2 f0 = __half22float2(xo2[(long)r * 64 + c2]);
    float2 f1 = __half22float2(xo2[(long)(r + 4) * 64 + c2]);
    ax += f0.x; ay += f0.y; bx2 += f1.x; by2 += f1.y;
  }
  for (; r < qhi; r += 4) {
    float2 f0 = __half22float2(xo2[(long)r * 64 + c2]);
    ax += f0.x; ay += f0.y;
  }
  __shared__ float2 sp[256];
  sp[t] = make_float2(ax + bx2, ay + by2);
  __syncthreads();
  if (t < 64) {
    float2 s0 = sp[t], s1 = sp[t + 64], s2 = sp[t + 128], s3 = sp[t + 192];
    float* dst = pool_part + ((long)(b * 4 + q)) * HC;
    dst[2 * t] = (s0.x + s1.x) + (s2.x + s3.x);
    dst[2 * t + 1] = (s0.y + s1.y) + (s2.y + s3.y);
  }
}

__global__ void k_final(const float* __restrict__ pool_part, const int* __restrict__ batch,
                        const float* __restrict__ lin_w, const float* __restrict__ lin_b,
                        float* __restrict__ out, int N, int B) {
  int b = blockIdx.x;
  __shared__ float pl[HC];
  __shared__ int bounds[2];
  int t = threadIdx.x;
  if (t < 2) bounds[t] = lowerb(batch, N, b + t);
  __syncthreads();
  float c = fmaxf((float)(bounds[1] - bounds[0]), 1.0f);
  const float* pp = pool_part + (long)b * 4 * HC;
  pl[t] = (pp[t] + pp[HC + t] + pp[2 * HC + t] + pp[3 * HC + t]) / c;
  __syncthreads();
  if (t < 10) {
    float a = lin_b[t];
    for (int k = 0; k < HC; ++k) a = fmaf(pl[k], lin_w[t * HC + k], a);
    out[b * 10 + t] = a;
  }
}

extern "C" void kernel_launch(void* const* d_in, const int* in_sizes, int n_in,
                              void* d_out, int out_size, void* d_ws, size_t ws_size,
                              hipStream_t stream) {
  const float* x = (const float*)d_in[0];
  const int* ei = (const int*)d_in[1];
  const int* batch = (const int*)d_in[2];
  const float* Wm = (const float*)d_in[4];
  const float* att_s = (const float*)d_in[5];
  const float* att_d = (const float*)d_in[6];
  const float* bias = (const float*)d_in[7];
  const float* lin_w = (const float*)d_in[8];
  const float* lin_b = (const float*)d_in[9];
  float* out = (float*)d_out;

  const int N = in_sizes[2];
  const int E = in_sizes[1] / 2;
  const int B = out_size / 10;
  const int NBUCK = (N + 511) >> 9;        // dst buckets (<=512)
  const int M = NBUCK * NBLK_P;            // hist entries
  const int NB2 = (M + 255) / 256;         // hist-scan blocks (<=1024)
  const int CH = (E + NBLK_P - 1) / NBLK_P;

  char* p = (char*)d_ws;
  auto carve = [&](size_t bytes) {
    void* r = (void*)p;
    p += (bytes + 255) & ~(size_t)255;
    return r;
  };
  __half* xh = (__half*)carve((size_t)N * HC * 2);
  __half* xout = (__half*)carve((size_t)N * HC * 2);
  float* a_src = (float*)carve((size_t)N * NHEAD * 4);
  float* a_dst = (float*)carve((size_t)N * NHEAD * 4);
  int* offs = (int*)carve((size_t)(N + 1) * 4);
  int* csr_src = (int*)carve((size_t)(N + (size_t)E) * 4);
  float* pool_part = (float*)carve((size_t)B * 4 * HC * 4);
  _Float16* Wh = (_Float16*)carve((size_t)9 * 4 * 64 * 8 * 2);

  // alias partition scratch into xout (consumed by k_build before k_agg writes xout)
  char* q = (char*)xout;
  auto carve2 = [&](size_t bytes) {
    void* r = (void*)q;
    q += (bytes + 255) & ~(size_t)255;
    return r;
  };
  unsigned* ebuf = (unsigned*)carve2((size_t)E * 4);
  int* hist = (int*)carve2((size_t)M * 4);
  int* histoffs = (int*)carve2((size_t)(M + 1) * 4);
  int* part2 = (int*)carve2((size_t)(NB2 + 2) * 4);

  k_wprep<<<9, 256, 0, stream>>>(Wm, att_s, att_d, Wh);
  k_xw<<<(N + 63) / 64, 256, 0, stream>>>(x, Wh, (_Float16*)xh, a_src, a_dst, N);
  k_hist<<<NBLK_P, 256, 0, stream>>>(ei, hist, E, NBUCK, CH);
  k_scanA<<<NB2, 256, 0, stream>>>(hist, histoffs, part2, M);
  k_scanB<<<1, 1024, 0, stream>>>(part2, NB2);
  k_scanC<<<(M + 256) / 256, 256, 0, stream>>>(histoffs, part2, M, NB2);
  k_part<<<NBLK_P, 256, 0, stream>>>(ei, histoffs, ebuf, E, NBUCK, CH);
  k_build<<<NBUCK, 256, 0, stream>>>(histoffs, ebuf, csr_src, offs, N);
  k_agg<<<(N + 3) / 4, 256, 0, stream>>>(csr_src, offs, a_src, a_dst, xh, bias, xout, N);
  k_pool<<<dim3(B, 4), 256, 0, stream>>>(xout, batch, pool_part, N);
  k_final<<<B, 128, 0, stream>>>(pool_part, batch, lin_w, lin_b, out, N, B);
}